// Round 12
// baseline (2281.175 us; speedup 1.0000x reference)
//
#include <hip/hip_runtime.h>
#include <hip/hip_bf16.h>
#include <math.h>

// ---- problem constants ----
#define LTOT 4161
#define BATCH 4
#define NROWS (BATCH*LTOT)      // 16644
#define NPAD1 3456
#define DM 768
#define DI 1536
#define DIP 3352
#define ZLD 3328
#define NH 24
#define HD 64
#define DS 128
#define EPSF 1e-5f
#define CHK 128
#define NCH 33
#define NBLK (BATCH*NCH*NH)     // 3168
#define LDF 136
#define XLD 72
#define RLD 264

typedef __attribute__((ext_vector_type(8))) __bf16 bf16x8;
typedef __attribute__((ext_vector_type(4))) float f32x4;
typedef __attribute__((ext_vector_type(8))) short short8;
typedef __attribute__((ext_vector_type(4))) unsigned int u32x4;
typedef unsigned short u16;
typedef unsigned int u32;

static __device__ __forceinline__ u16 f2bf(float f){
  unsigned u = __builtin_bit_cast(unsigned, f);
  u += 0x7FFFu + ((u >> 16) & 1u);          // RNE
  return (u16)(u >> 16);
}
static __device__ __forceinline__ float bf2f(u16 v){
  return __builtin_bit_cast(float, ((unsigned)v) << 16);
}
static __device__ __forceinline__ float siluf(float v){ return v / (1.f + __expf(-v)); }

// bijective XCD-chunking remap (m204)
static __device__ __forceinline__ int xcd_swz(int orig, int nwg){
  int xcd = orig & 7;
  int idx = orig >> 3;
  int q = nwg >> 3, r = nwg & 7;
  int base = (xcd < r) ? xcd*(q + 1) : r*(q + 1) + (xcd - r)*q;
  return base + idx;
}

__device__ __forceinline__ float blockSum256(float v, float* sh){
  #pragma unroll
  for (int o = 32; o > 0; o >>= 1) v += __shfl_down(v, o);
  int w = threadIdx.x >> 6;
  if ((threadIdx.x & 63) == 0) sh[w] = v;
  __syncthreads();
  v = sh[0] + sh[1] + sh[2] + sh[3];
  __syncthreads();
  return v;
}

// ---- build x = LN0(concat(s0, h8, zm)) ----
__global__ __launch_bounds__(256)
void build_x_kernel(const float* __restrict__ im8, const float* __restrict__ frw,
                    const float* __restrict__ frb, const float* __restrict__ s0,
                    const float* __restrict__ suffix, const float* __restrict__ w,
                    const float* __restrict__ bb, float* __restrict__ x)
{
  int row = blockIdx.x;
  int b = row / LTOT, l = row % LTOT;
  int t = threadIdx.x;
  __shared__ float sh[4];
  float v[3];
  if (l == 0) {
    #pragma unroll
    for (int i = 0; i < 3; i++) v[i] = s0[t + i*256];
  } else if (l <= 64) {
    int p = l - 1;
    float r0 = im8[(b*64 + p)*3 + 0], r1 = im8[(b*64 + p)*3 + 1], r2 = im8[(b*64 + p)*3 + 2];
    #pragma unroll
    for (int i = 0; i < 3; i++) {
      int d = t + i*256;
      v[i] = r0*frw[d] + r1*frw[768 + d] + r2*frw[1536 + d] + frb[d];
    }
  } else {
    int j = l - 65;
    int p = ((j >> 9) << 3) | ((j & 63) >> 3);
    float r0 = im8[(b*64 + p)*3 + 0], r1 = im8[(b*64 + p)*3 + 1], r2 = im8[(b*64 + p)*3 + 2];
    #pragma unroll
    for (int i = 0; i < 3; i++) {
      int d = t + i*256;
      v[i] = r0*frw[d] + r1*frw[768 + d] + r2*frw[1536 + d] + frb[d] + suffix[(size_t)j*768 + d];
    }
  }
  float s = v[0] + v[1] + v[2];
  s = blockSum256(s, sh);
  float mu = s * (1.f/768.f);
  float q = 0;
  #pragma unroll
  for (int i = 0; i < 3; i++) { float d = v[i] - mu; q += d*d; }
  q = blockSum256(q, sh);
  float rs = rsqrtf(q * (1.f/768.f) + EPSF);
  float* xr = x + (size_t)row*DM;
  #pragma unroll
  for (int i = 0; i < 3; i++) {
    int d = t + i*256;
    xr[d] = (v[i] - mu)*rs*w[d] + bb[d];
  }
}

// ---- per-layer LN -> bf16 ----
__global__ __launch_bounds__(256)
void ln_bf16_kernel(const float* __restrict__ x, const float* __restrict__ w,
                    const float* __restrict__ bb, u16* __restrict__ out)
{
  int row = blockIdx.x;
  int t = threadIdx.x;
  __shared__ float sh[4];
  const float* xr = x + (size_t)row*DM;
  float v[3];
  #pragma unroll
  for (int i = 0; i < 3; i++) v[i] = xr[t + i*256];
  float s = v[0] + v[1] + v[2];
  s = blockSum256(s, sh);
  float mu = s * (1.f/768.f);
  float q = 0;
  #pragma unroll
  for (int i = 0; i < 3; i++) { float d = v[i] - mu; q += d*d; }
  q = blockSum256(q, sh);
  float rs = rsqrtf(q * (1.f/768.f) + EPSF);
  u16* orow = out + (size_t)row*DM;
  #pragma unroll
  for (int i = 0; i < 3; i++) {
    int d = t + i*256;
    orow[d] = f2bf((v[i] - mu)*rs*w[d] + bb[d]);
  }
}

// ---- transpose + f32->bf16 ----
__global__ __launch_bounds__(256)
void transp_bf16(const float* __restrict__ in, u16* __restrict__ out, int K, int N)
{
  __shared__ float tl[32][33];
  int tx = threadIdx.x & 31, ty = threadIdx.x >> 5;
  int n0 = blockIdx.x * 32, k0 = blockIdx.y * 32;
  #pragma unroll
  for (int r = 0; r < 4; r++) {
    int k = k0 + ty + r*8, n = n0 + tx;
    tl[ty + r*8][tx] = (n < N) ? in[(size_t)k*N + n] : 0.f;
  }
  __syncthreads();
  #pragma unroll
  for (int r = 0; r < 4; r++) {
    int n = n0 + ty + r*8, k = k0 + tx;
    out[(size_t)n*K + k] = f2bf(tl[tx][ty + r*8]);
  }
}

#define LD8(p) (*(const short8*)(p))

// ---- GEMM0: zx = xn @ Wi ; 256x128 tile, 8 waves, BK=32 double-buffered ----
__global__ __launch_bounds__(512, 2)
void gemm0(const u16* __restrict__ A, const u16* __restrict__ BT,
           u16* __restrict__ zxO, const float* __restrict__ dtbias,
           float* __restrict__ dtO)
{
  __shared__ __align__(16) u16 As[2][256*40];
  __shared__ __align__(16) u16 Bs[2][128*40];
  const int t = threadIdx.x;
  const int nid = xcd_swz(blockIdx.y*27 + blockIdx.x, 27*66);
  const int bm = nid / 27, bn = nid % 27;
  const int lane = t & 63, wave = t >> 6;
  const int wr = wave >> 1, wc = wave & 1;      // wr 0..3 (64-row slab), wc 0..1 (64-col slab)
  const int r16 = lane & 15, kb = lane >> 4;

  const int m = t >> 1, half = t & 1;
  const int grow = bm*256 + m;
  const bool valid = grow < NROWS;
  const u16* gA = A + (size_t)(valid ? grow : 0)*DM + half*16;
  const int wofsA = m*40 + half*16;
  const int brow = t >> 2, bq = t & 3;
  const u16* gB = BT + (size_t)(bn*128 + brow)*DM + bq*8;
  const int wofsB = brow*40 + bq*8;

  short8 a0 = {}, a1 = {}, b0;
  b0 = LD8(gB);
  if (valid) { a0 = LD8(gA); a1 = LD8(gA + 8); }
  *(short8*)&As[0][wofsA] = a0; *(short8*)&As[0][wofsA + 8] = a1;
  *(short8*)&Bs[0][wofsB] = b0;
  __syncthreads();

  f32x4 acc[4][4] = {};
  int p = 0;
  for (int kt = 0; kt < DM; kt += 32) {
    const bool more = (kt + 32 < DM);
    if (more) {
      b0 = LD8(gB + kt + 32);
      if (valid) { a0 = LD8(gA + kt + 32); a1 = LD8(gA + kt + 40); }
    }
    bf16x8 af[4], bfr[4];
    #pragma unroll
    for (int i = 0; i < 4; i++) af[i]  = *(const bf16x8*)&As[p][(wr*64 + i*16 + r16)*40 + kb*8];
    #pragma unroll
    for (int i = 0; i < 4; i++) bfr[i] = *(const bf16x8*)&Bs[p][(wc*64 + i*16 + r16)*40 + kb*8];
    #pragma unroll
    for (int i = 0; i < 4; i++)
      #pragma unroll
      for (int j = 0; j < 4; j++)
        acc[i][j] = __builtin_amdgcn_mfma_f32_16x16x32_bf16(af[i], bfr[j], acc[i][j], 0, 0, 0);
    if (more) {
      *(short8*)&As[p^1][wofsA] = a0; *(short8*)&As[p^1][wofsA + 8] = a1;
      *(short8*)&Bs[p^1][wofsB] = b0;
    }
    __syncthreads();
    p ^= 1;
  }
  const int rbase = bm*256 + wr*64, cbase = bn*128 + wc*64;
  #pragma unroll
  for (int i = 0; i < 4; i++) {
    #pragma unroll
    for (int j = 0; j < 4; j++) {
      int col = cbase + j*16 + r16;
      #pragma unroll
      for (int e = 0; e < 4; e++) {
        int row = rbase + i*16 + kb*4 + e;
        if (row < NROWS) {
          float v = acc[i][j][e];
          if (col < ZLD) {
            zxO[(size_t)row*ZLD + col] = f2bf(v);
          } else if (col < DIP) {
            int hh = col - ZLD;
            float d = v + dtbias[hh];
            d = (d > 20.f) ? d : log1pf(expf(d));
            dtO[(size_t)row*NH + hh] = d;
          }
        }
      }
    }
  }
}

// ---- GEMM1: x += rmsnorm-scaled gated zx @ Wo ; 128x128, BK=32 dbuf; rs*gw fused ----
__global__ __launch_bounds__(256)
void gemm_out(const u16* __restrict__ A, const float* __restrict__ rsb,
              const float* __restrict__ gw, const u16* __restrict__ BT,
              float* __restrict__ X)
{
  __shared__ __align__(16) u16 As[2][128*40];
  __shared__ __align__(16) u16 Bs[2][128*40];
  __shared__ float gwl[DI];
  const int t = threadIdx.x;
  const int nid = xcd_swz(blockIdx.y*6 + blockIdx.x, 6*131);
  const int bm = nid / 6, bn = nid % 6;
  const int lane = t & 63, wave = t >> 6;
  const int wr = wave >> 1, wc = wave & 1;
  const int r16 = lane & 15, kb = lane >> 4;

  for (int i = t; i < DI; i += 256) gwl[i] = gw[i];

  const int m = t >> 1, half = t & 1;
  const int grow = bm*128 + m;
  const bool valid = grow < NROWS;
  const float rs = valid ? rsb[grow] : 0.f;
  const u16* gA = A + (size_t)(valid ? grow : 0)*ZLD + half*16;
  const u16* gB = BT + (size_t)(bn*128 + m)*DI + half*16;
  const int wofs = m*40 + half*16;

  short8 ra0 = {}, ra1 = {}, b0, b1;
  b0 = LD8(gB); b1 = LD8(gB + 8);
  if (valid) { ra0 = LD8(gA); ra1 = LD8(gA + 8); }
  __syncthreads();                       // gwl visible
  {
    const int c0 = half*16;
    short8 ta0, ta1;
    #pragma unroll
    for (int j = 0; j < 8; j++) ta0[j] = (short)f2bf(bf2f((u16)ra0[j]) * rs * gwl[c0 + j]);
    #pragma unroll
    for (int j = 0; j < 8; j++) ta1[j] = (short)f2bf(bf2f((u16)ra1[j]) * rs * gwl[c0 + 8 + j]);
    *(short8*)&As[0][wofs] = ta0; *(short8*)&As[0][wofs + 8] = ta1;
    *(short8*)&Bs[0][wofs] = b0;  *(short8*)&Bs[0][wofs + 8] = b1;
  }
  __syncthreads();

  f32x4 acc[4][4] = {};
  int p = 0;
  for (int kt = 0; kt < DI; kt += 32) {
    const bool more = (kt + 32 < DI);
    if (more) {
      b0 = LD8(gB + kt + 32); b1 = LD8(gB + kt + 40);
      if (valid) { ra0 = LD8(gA + kt + 32); ra1 = LD8(gA + kt + 40); }
    }
    bf16x8 af[4], bfr[4];
    #pragma unroll
    for (int i = 0; i < 4; i++) af[i]  = *(const bf16x8*)&As[p][(wr*64 + i*16 + r16)*40 + kb*8];
    #pragma unroll
    for (int i = 0; i < 4; i++) bfr[i] = *(const bf16x8*)&Bs[p][(wc*64 + i*16 + r16)*40 + kb*8];
    #pragma unroll
    for (int i = 0; i < 4; i++)
      #pragma unroll
      for (int j = 0; j < 4; j++)
        acc[i][j] = __builtin_amdgcn_mfma_f32_16x16x32_bf16(af[i], bfr[j], acc[i][j], 0, 0, 0);
    if (more) {
      const int c0 = kt + 32 + half*16;
      short8 ta0, ta1;
      #pragma unroll
      for (int j = 0; j < 8; j++) ta0[j] = (short)f2bf(bf2f((u16)ra0[j]) * rs * gwl[c0 + j]);
      #pragma unroll
      for (int j = 0; j < 8; j++) ta1[j] = (short)f2bf(bf2f((u16)ra1[j]) * rs * gwl[c0 + 8 + j]);
      *(short8*)&As[p^1][wofs] = ta0; *(short8*)&As[p^1][wofs + 8] = ta1;
      *(short8*)&Bs[p^1][wofs] = b0;  *(short8*)&Bs[p^1][wofs + 8] = b1;
    }
    __syncthreads();
    p ^= 1;
  }
  const int rbase = bm*128 + wr*64, cbase = bn*128 + wc*64;
  #pragma unroll
  for (int i = 0; i < 4; i++) {
    #pragma unroll
    for (int j = 0; j < 4; j++) {
      int col = cbase + j*16 + r16;
      #pragma unroll
      for (int e = 0; e < 4; e++) {
        int row = rbase + i*16 + kb*4 + e;
        if (row < NROWS) X[(size_t)row*DM + col] += acc[i][j][e];
      }
    }
  }
}

// ======================= chunked SSD =======================

// ---- dtcs: per (b,c,h) prefix sums & weights ----
__global__ __launch_bounds__(128)
void dtcs_kernel(const float* __restrict__ dt, const float* __restrict__ alog,
                 float* __restrict__ csb, float* __restrict__ dtvb,
                 float* __restrict__ wjsb, float* __restrict__ dtot)
{
  const int id = blockIdx.x;
  const int h = id % NH; const int c = (id / NH) % NCH; const int b = id / (NH*NCH);
  const int t = threadIdx.x;
  const int base = c*CHK;
  int rows = LTOT - base; if (rows > CHK) rows = CHK;
  __shared__ float cs[128];
  float dv = 0.f;
  if (t < rows) dv = dt[(size_t)(b*LTOT + base + t)*NH + h];
  const float aexp = __expf(alog[h]);
  cs[t] = -dv * aexp;
  __syncthreads();
  for (int off = 1; off < 128; off <<= 1) {
    float add = (t >= off) ? cs[t - off] : 0.f;
    __syncthreads();
    cs[t] += add;
    __syncthreads();
  }
  float csl = cs[127];
  size_t o = (size_t)id*128 + t;
  csb[o] = cs[t];
  dtvb[o] = dv;
  wjsb[o] = __expf(csl - cs[t]) * dv;
  if (t == 0) dtot[id] = __expf(csl);
}

// ---- conv B/C once per (b,chunk); ALSO computes Sraw = C @ B^T (head-independent) ----
__global__ __launch_bounds__(256)
void convBC_kernel(const u16* __restrict__ zx, const float* __restrict__ cw,
                   const float* __restrict__ cb, u16* __restrict__ Ccv,
                   u16* __restrict__ BcvT, u16* __restrict__ Sraw)
{
  const int bc = xcd_swz(blockIdx.x, BATCH*NCH);
  const int b = bc / NCH, c = bc % NCH;
  const int t = threadIdx.x;
  const int base = c*CHK;
  __shared__ __align__(16) u16 raw[131*RLD + 8];
  __shared__ __align__(16) u16 Bt[128*LDF];
  __shared__ __align__(16) u16 Ct[128*LDF];
  const u16* zb = zx + (size_t)(b*LTOT)*ZLD;

  #pragma unroll
  for (int rg = 0; rg < 17; rg++) {
    int idx = rg*256 + t;
    int r = idx >> 5, seg = idx & 31;
    if (r < 131) {
      int g = base - 3 + r;
      short8 v = {};
      if (g >= 0 && g < LTOT) v = LD8(zb + (size_t)g*ZLD + 3072 + seg*8);
      *(short8*)&raw[r*RLD + seg*8] = v;
    }
  }
  __syncthreads();
  {
    const int isC = t >> 7, n = t & 127;
    const int ch = 1536 + t;
    float w0 = cw[ch*4+0], w1 = cw[ch*4+1], w2 = cw[ch*4+2], w3 = cw[ch*4+3];
    float bias = cb[ch];
    float r0 = bf2f(raw[0*RLD + t]);
    float r1 = bf2f(raw[1*RLD + t]);
    float r2 = bf2f(raw[2*RLD + t]);
    u16* dstT = isC ? Ct : Bt;
    #pragma unroll 4
    for (int j = 0; j < 128; j++) {
      float r3 = bf2f(raw[(j + 3)*RLD + t]);
      float o = bias + w0*r0 + w1*r1 + w2*r2 + w3*r3;
      dstT[j*LDF + n] = f2bf(siluf(o));
      r0 = r1; r1 = r2; r2 = r3;
    }
  }
  __syncthreads();
  // write Ccv [l][n]
  #pragma unroll
  for (int rg = 0; rg < 8; rg++) {
    int idx = rg*256 + t;
    int r = idx >> 4, seg = idx & 15;
    int g = base + r;
    if (g < LTOT)
      *(short8*)(Ccv + (size_t)(b*LTOT + g)*128 + seg*8) = *(const short8*)&Ct[r*LDF + seg*8];
  }
  // write BcvT [n][j]
  u16* bT = BcvT + (size_t)bc*16384;
  #pragma unroll
  for (int rg = 0; rg < 8; rg++) {
    int idx = rg*256 + t;
    int n = idx >> 4, js = (idx & 15)*8;
    short8 v;
    #pragma unroll
    for (int k = 0; k < 8; k++) v[k] = (short)Bt[(js + k)*LDF + n];
    *(short8*)(bT + n*128 + js) = v;
  }
  // Sraw[i][j] = sum_n Ct[i][n]*Bt[j][n] (once per (b,c), shared by all 24 heads)
  {
    const int lane = t & 63, wave = t >> 6;
    const int r16 = lane & 15, kb = lane >> 4;
    f32x4 acc[2][8] = {};
    #pragma unroll
    for (int kt = 0; kt < 4; kt++) {
      bf16x8 af[2], bfr[8];
      #pragma unroll
      for (int m2 = 0; m2 < 2; m2++) af[m2] = *(const bf16x8*)&Ct[(wave*32 + m2*16 + r16)*LDF + kt*32 + kb*8];
      #pragma unroll
      for (int nj = 0; nj < 8; nj++) bfr[nj] = *(const bf16x8*)&Bt[(nj*16 + r16)*LDF + kt*32 + kb*8];
      #pragma unroll
      for (int m2 = 0; m2 < 2; m2++)
        #pragma unroll
        for (int nj = 0; nj < 8; nj++)
          acc[m2][nj] = __builtin_amdgcn_mfma_f32_16x16x32_bf16(af[m2], bfr[nj], acc[m2][nj], 0, 0, 0);
    }
    u16* sdst = Sraw + (size_t)bc*16384;
    #pragma unroll
    for (int m2 = 0; m2 < 2; m2++)
      #pragma unroll
      for (int nj = 0; nj < 8; nj++)
        #pragma unroll
        for (int e = 0; e < 4; e++) {
          int i = wave*32 + m2*16 + kb*4 + e;
          int j = nj*16 + r16;
          sdst[i*128 + j] = f2bf(acc[m2][nj][e]);
        }
  }
}

// ---- K1: per-chunk state ----
__global__ __launch_bounds__(256)
void chunk_state_kernel(const u16* __restrict__ zx, const float* __restrict__ wjsb,
                        const float* __restrict__ cw, const float* __restrict__ cb,
                        const u16* __restrict__ BcvT, u16* __restrict__ cstat)
{
  const int id = xcd_swz(blockIdx.x, NBLK);
  const int h = id % NH; const int c = (id / NH) % NCH; const int b = id / (NH*NCH);
  const int t = threadIdx.x;
  const int base = c*CHK;

  __shared__ __align__(16) u16 Bbuf[128*LDF];
  __shared__ __align__(16) u16 xbuf[131*XLD + 8];
  __shared__ float wjs[128];

  const u16* zb = zx + (size_t)(b*LTOT)*ZLD;
  if (t < 128) wjs[t] = wjsb[(size_t)id*128 + t];
  {
    const u16* bT = BcvT + (size_t)(b*NCH + c)*16384;
    #pragma unroll
    for (int rg = 0; rg < 8; rg++) {
      int idx = rg*256 + t;
      int n = idx >> 4, js = (idx & 15)*8;
      *(short8*)&Bbuf[n*LDF + js] = LD8(bT + n*128 + js);
    }
  }
  #pragma unroll
  for (int rg = 0; rg < 5; rg++) {
    int r = rg*32 + (t >> 3);
    int seg = t & 7;
    if (r < 131) {
      int g = base - 3 + r;
      short8 v = {};
      if (g >= 0 && g < LTOT) v = LD8(zb + (size_t)g*ZLD + 1536 + h*HD + seg*8);
      *(short8*)&xbuf[r*XLD + seg*8] = v;
    }
  }
  __syncthreads();

  const int p_ = t & 63, jq = t >> 6;
  u32 pkx[16];
  {
    const int ch = h*HD + p_;
    float w0 = cw[ch*4+0], w1 = cw[ch*4+1], w2 = cw[ch*4+2], w3 = cw[ch*4+3];
    float bias = cb[ch];
    const int rb = jq*32;
    float r0 = bf2f(xbuf[(rb+0)*XLD + p_]);
    float r1 = bf2f(xbuf[(rb+1)*XLD + p_]);
    float r2 = bf2f(xbuf[(rb+2)*XLD + p_]);
    #pragma unroll
    for (int k2 = 0; k2 < 16; k2++) {
      float r3 = bf2f(xbuf[(rb + 2*k2 + 3)*XLD + p_]);
      float o0 = bias + w0*r0 + w1*r1 + w2*r2 + w3*r3;
      float r4 = bf2f(xbuf[(rb + 2*k2 + 4)*XLD + p_]);
      float o1 = bias + w0*r1 + w1*r2 + w2*r3 + w3*r4;
      float s0 = siluf(o0) * wjs[rb + 2*k2];
      float s1 = siluf(o1) * wjs[rb + 2*k2 + 1];
      pkx[k2] = (u32)f2bf(s0) | ((u32)f2bf(s1) << 16);
      r0 = r2; r1 = r3; r2 = r4;
    }
  }
  __syncthreads();
  #pragma unroll
  for (int q = 0; q < 4; q++) {
    u32x4 v; v[0] = pkx[q*4]; v[1] = pkx[q*4+1]; v[2] = pkx[q*4+2]; v[3] = pkx[q*4+3];
    *(u32x4*)&xbuf[p_*LDF + jq*32 + q*8] = v;
  }
  __syncthreads();

  const int lane = t & 63, wave = t >> 6;
  const int r16 = lane & 15, kb = lane >> 4;
  const int n0 = wave*32;
  f32x4 acc[4][2] = {};
  #pragma unroll
  for (int kt = 0; kt < 4; kt++) {
    bf16x8 af[4], bfr[2];
    #pragma unroll
    for (int m = 0; m < 4; m++) af[m] = *(const bf16x8*)&xbuf[(m*16 + r16)*LDF + kt*32 + kb*8];
    #pragma unroll
    for (int nn = 0; nn < 2; nn++) bfr[nn] = *(const bf16x8*)&Bbuf[(n0 + nn*16 + r16)*LDF + kt*32 + kb*8];
    #pragma unroll
    for (int m = 0; m < 4; m++)
      #pragma unroll
      for (int nn = 0; nn < 2; nn++)
        acc[m][nn] = __builtin_amdgcn_mfma_f32_16x16x32_bf16(af[m], bfr[nn], acc[m][nn], 0, 0, 0);
  }
  u16* dst = cstat + (size_t)id*64*128;
  #pragma unroll
  for (int m = 0; m < 4; m++)
    #pragma unroll
    for (int nn = 0; nn < 2; nn++)
      #pragma unroll
      for (int e = 0; e < 4; e++) {
        int p = m*16 + kb*4 + e;
        int n = n0 + nn*16 + r16;
        dst[p*128 + n] = f2bf(acc[m][nn][e]);
      }
}

// ---- K2: inter-chunk scan ----
__global__ __launch_bounds__(256)
void state_scan_kernel(u16* __restrict__ cstat, const float* __restrict__ dtot)
{
  const int b = blockIdx.x / NH, h = blockIdx.x % NH;
  const int t = threadIdx.x;
  float run[32];
  #pragma unroll
  for (int k = 0; k < 32; k++) run[k] = 0.f;
  size_t id0 = (size_t)(b*NCH)*NH + h;
  short8 cur[4];
  {
    const u16* s0 = cstat + id0*8192 + t*32;
    #pragma unroll
    for (int q = 0; q < 4; q++) cur[q] = LD8(s0 + q*8);
  }
  float d = dtot[id0];
  for (int c = 0; c < NCH; ++c) {
    size_t id = (size_t)(b*NCH + c)*NH + h;
    u16* slab = cstat + id*8192 + t*32;
    short8 nxt[4] = {}; float nd = 0.f;
    if (c + 1 < NCH) {
      const u16* sn = slab + (size_t)NH*8192;
      #pragma unroll
      for (int q = 0; q < 4; q++) nxt[q] = LD8(sn + q*8);
      nd = dtot[id + NH];
    }
    short8 out[4];
    #pragma unroll
    for (int q = 0; q < 4; q++)
      #pragma unroll
      for (int k = 0; k < 8; k++) {
        int idx = q*8 + k;
        float csv = bf2f((u16)cur[q][k]);
        out[q][k] = (short)f2bf(run[idx]);
        run[idx] = run[idx]*d + csv;
      }
    #pragma unroll
    for (int q = 0; q < 4; q++) *(short8*)(slab + q*8) = out[q];
    #pragma unroll
    for (int q = 0; q < 4; q++) cur[q] = nxt[q];
    d = nd;
  }
}

// ---- K3: per-chunk output; Phase A replaced by masked staging of precomputed Sraw ----
__global__ __launch_bounds__(512, 4)
void chunk_output_kernel(u16* __restrict__ zx, const float* __restrict__ csb,
                         const float* __restrict__ dtvb, const float* __restrict__ cw,
                         const float* __restrict__ cb, const float* __restrict__ Dvec,
                         const u16* __restrict__ Sraw, const u16* __restrict__ Ccv,
                         const u16* __restrict__ cstat)
{
  const int id = xcd_swz(blockIdx.x, NBLK);
  const int h = id % NH; const int c = (id / NH) % NCH; const int b = id / (NH*NCH);
  const int t = threadIdx.x;
  const int base = c*CHK;
  int rows = LTOT - base; if (rows > CHK) rows = CHK;

  __shared__ __align__(16) u16 Bc[128*LDF];       // P[i][j]
  __shared__ __align__(16) u16 stT[64*LDF];       // state_before [p][n]
  __shared__ __align__(16) u16 xbuf[131*XLD + 8]; // raw x -> xc[p][j]
  __shared__ float dtv[128];
  __shared__ float cs[128];

  const u16* zb = zx + (size_t)(b*LTOT)*ZLD;
  const size_t crow0 = (size_t)(b*LTOT)*128;
  if (t < 128) {
    cs[t]  = csb[(size_t)id*128 + t];
    dtv[t] = dtvb[(size_t)id*128 + t];
  }
  {
    const u16* slab = cstat + (size_t)id*8192;
    int p = t >> 3, nb = (t & 7)*16;
    *(short8*)&stT[p*LDF + nb]     = LD8(slab + p*128 + nb);
    *(short8*)&stT[p*LDF + nb + 8] = LD8(slab + p*128 + nb + 8);
  }
  #pragma unroll
  for (int rg = 0; rg < 3; rg++) {
    int r = rg*64 + (t >> 3);
    int seg = t & 7;
    if (r < 131) {
      int g = base - 3 + r;
      short8 v = {};
      if (g >= 0 && g < LTOT) v = LD8(zb + (size_t)g*ZLD + 1536 + h*HD + seg*8);
      *(short8*)&xbuf[r*XLD + seg*8] = v;
    }
  }
  __syncthreads();

  // x conv -> regs  ||  P staging: load Sraw, apply per-head mask, write LDS
  const int p_ = t & 63, jq = t >> 6;
  u32 pkx[8];
  {
    const int ch = h*HD + p_;
    float w0 = cw[ch*4+0], w1 = cw[ch*4+1], w2 = cw[ch*4+2], w3 = cw[ch*4+3];
    float bias = cb[ch];
    const int rb = jq*16;
    float r0 = bf2f(xbuf[(rb+0)*XLD + p_]);
    float r1 = bf2f(xbuf[(rb+1)*XLD + p_]);
    float r2 = bf2f(xbuf[(rb+2)*XLD + p_]);
    #pragma unroll
    for (int k2 = 0; k2 < 8; k2++) {
      float r3 = bf2f(xbuf[(rb + 2*k2 + 3)*XLD + p_]);
      float o0 = bias + w0*r0 + w1*r1 + w2*r2 + w3*r3;
      float r4 = bf2f(xbuf[(rb + 2*k2 + 4)*XLD + p_]);
      float o1 = bias + w0*r1 + w1*r2 + w2*r3 + w3*r4;
      int j0 = rb + 2*k2;
      u32 lo = (j0     < rows) ? (u32)f2bf(siluf(o0)) : 0u;
      u32 hi = (j0 + 1 < rows) ? (u32)f2bf(siluf(o1)) : 0u;
      pkx[k2] = lo | (hi << 16);
      r0 = r2; r1 = r3; r2 = r4;
    }
  }
  {
    const u16* sS = Sraw + (size_t)(b*NCH + c)*16384;
    #pragma unroll
    for (int q = 0; q < 4; q++) {
      int idx = q*512 + t;
      int i = idx >> 4, seg = (idx & 15)*8;
      short8 s = LD8(sS + i*128 + seg);
      float csi = cs[i];
      short8 o;
      #pragma unroll
      for (int k = 0; k < 8; k++) {
        int j = seg + k;
        float f = 0.f;
        if (j <= i && i < rows) f = __expf(csi - cs[j]) * dtv[j];
        o[k] = (short)f2bf(bf2f((u16)s[k]) * f);
      }
      *(short8*)&Bc[i*LDF + seg] = o;
    }
  }
  __syncthreads();
  {
    u32x4 v0; v0[0] = pkx[0]; v0[1] = pkx[1]; v0[2] = pkx[2]; v0[3] = pkx[3];
    u32x4 v1; v1[0] = pkx[4]; v1[1] = pkx[5]; v1[2] = pkx[6]; v1[3] = pkx[7];
    *(u32x4*)&xbuf[p_*LDF + jq*16]     = v0;
    *(u32x4*)&xbuf[p_*LDF + jq*16 + 8] = v1;
  }
  __syncthreads();

  const int lane = t & 63, wave = t >> 6;
  const int r16 = lane & 15, kb = lane >> 4;

  // Phase B: Y1 = P @ xc^T ; Phase C: Y2 = C @ st^T (C direct from global) ; epilogue
  {
    const int iq = wave;
    bf16x8 cF[4];
    {
      int i = iq*16 + r16;
      int g = base + i; if (g >= LTOT) g = base;
      #pragma unroll
      for (int kt = 0; kt < 4; kt++)
        cF[kt] = *(const bf16x8*)(Ccv + crow0 + (size_t)g*128 + kt*32 + kb*8);
    }
    f32x4 accY[4] = {};
    #pragma unroll
    for (int kt = 0; kt < 4; kt++) {
      bf16x8 af = *(const bf16x8*)&Bc[(iq*16 + r16)*LDF + kt*32 + kb*8];
      #pragma unroll
      for (int n = 0; n < 4; n++) {
        bf16x8 bfr = *(const bf16x8*)&xbuf[(n*16 + r16)*LDF + kt*32 + kb*8];
        accY[n] = __builtin_amdgcn_mfma_f32_16x16x32_bf16(af, bfr, accY[n], 0, 0, 0);
      }
    }
    f32x4 accS[4] = {};
    #pragma unroll
    for (int kt = 0; kt < 4; kt++) {
      #pragma unroll
      for (int n = 0; n < 4; n++) {
        bf16x8 bfr = *(const bf16x8*)&stT[(n*16 + r16)*LDF + kt*32 + kb*8];
        accS[n] = __builtin_amdgcn_mfma_f32_16x16x32_bf16(cF[kt], bfr, accS[n], 0, 0, 0);
      }
    }
    const float dcoef = Dvec[h];
    #pragma unroll
    for (int e = 0; e < 4; e++) {
      int i = iq*16 + kb*4 + e;
      if (i < rows) {
        float sc = __expf(cs[i]);
        size_t orow = (size_t)(b*LTOT + base + i)*ZLD + h*HD;
        #pragma unroll
        for (int n = 0; n < 4; n++) {
          int p = n*16 + r16;
          float xv = bf2f(xbuf[p*LDF + i]);
          float yv = accY[n][e] + sc*accS[n][e] + dcoef*xv;
          float zval = bf2f(zx[orow + p]);
          zx[orow + p] = f2bf(yv * siluf(zval));
        }
      }
    }
  }
}

// ---- rms stats ----
__global__ __launch_bounds__(256)
void rms_stats_kernel(const u16* __restrict__ zx, float* __restrict__ rsb)
{
  int row = blockIdx.x;
  int t = threadIdx.x;
  __shared__ float sh[4];
  float ss = 0.f;
  const u16* zr = zx + (size_t)row*ZLD;
  if (t < 192) {
    short8 v = LD8(zr + t*8);
    #pragma unroll
    for (int j = 0; j < 8; j++) { float f = bf2f((u16)v[j]); ss += f*f; }
  }
  ss = blockSum256(ss, sh);
  if (t == 0) rsb[row] = rsqrtf(ss * (1.f/1536.f) + EPSF);
}

// ---- head ----
__global__ __launch_bounds__(256)
void head_kernel(const float* __restrict__ x, const float* __restrict__ tw,
                 const float* __restrict__ tb, const float* __restrict__ im64,
                 float* __restrict__ out, float* __restrict__ partial)
{
  int bj = blockIdx.x;
  int b = bj >> 12, j = bj & 4095;
  int row = b*LTOT + 65 + j;
  const float* xr = x + (size_t)row*DM;
  int t = threadIdx.x;
  float p0 = 0, p1 = 0, p2 = 0;
  for (int k = t; k < 768; k += 256) {
    float xv = xr[k];
    p0 += xv*tw[k*3 + 0]; p1 += xv*tw[k*3 + 1]; p2 += xv*tw[k*3 + 2];
  }
  __shared__ float sh[4];
  p0 = blockSum256(p0, sh);
  p1 = blockSum256(p1, sh);
  p2 = blockSum256(p2, sh);
  if (t == 0) {
    float y0 = p0 + tb[0], y1 = p1 + tb[1], y2 = p2 + tb[2];
    size_t o = (size_t)bj*3;
    out[o] = y0; out[o + 1] = y1; out[o + 2] = y2;
    float d0 = y0 - im64[o], d1 = y1 - im64[o + 1], d2 = y2 - im64[o + 2];
    partial[bj] = d0*d0 + d1*d1 + d2*d2;
  }
}

__global__ __launch_bounds__(256)
void loss_reduce(const float* __restrict__ partial, float* __restrict__ out)
{
  int t = threadIdx.x;
  float s = 0.f;
  for (int i = t; i < BATCH*4096; i += 256) s += partial[i];
  __shared__ float sh[4];
  s = blockSum256(s, sh);
  if (t == 0) out[49152] = s * (1.f/49152.f);
}

// ---- launcher ----
static inline size_t alignup(size_t v){ return (v + 255) & ~(size_t)255; }

extern "C" void kernel_launch(void* const* d_in, const int* in_sizes, int n_in,
                              void* d_out, int out_size, void* d_ws, size_t ws_size,
                              hipStream_t stream)
{
  const float* im8        = (const float*)d_in[0];
  const float* im64       = (const float*)d_in[1];
  const float* from_rgb_w = (const float*)d_in[2];
  const float* from_rgb_b = (const float*)d_in[3];
  const float* to_rgb_w   = (const float*)d_in[4];
  const float* to_rgb_b   = (const float*)d_in[5];
  const float* s0         = (const float*)d_in[6];
  const float* suffix     = (const float*)d_in[7];
  const float* norm0_w    = (const float*)d_in[8];
  const float* norm0_b    = (const float*)d_in[9];
  const float* ln_w       = (const float*)d_in[10];
  const float* ln_b       = (const float*)d_in[11];
  const float* in_proj_w  = (const float*)d_in[12];
  const float* conv_w     = (const float*)d_in[13];
  const float* conv_b     = (const float*)d_in[14];
  const float* dt_bias    = (const float*)d_in[15];
  const float* A_log      = (const float*)d_in[16];
  const float* Dvec       = (const float*)d_in[17];
  const float* gn_w       = (const float*)d_in[18];
  const float* out_proj_w = (const float*)d_in[19];

  char* w = (char*)d_ws;
  size_t off = 0;
  float* x     = (float*)(w + off); off = alignup(off + (size_t)NROWS*DM*4);
  u16*   zx    = (u16*)  (w + off); off = alignup(off + (size_t)NROWS*ZLD*2);
  u16*   scr   = (u16*)  (w + off); off = alignup(off + (size_t)NBLK*64*128*2);
  u16*   Sraw  = (u16*)  (w + off); off = alignup(off + (size_t)BATCH*NCH*16384*2);
  u16*   Ccv   = (u16*)  (w + off); off = alignup(off + (size_t)NROWS*128*2);
  u16*   BcvT  = (u16*)  (w + off); off = alignup(off + (size_t)BATCH*NCH*16384*2);
  float* dt    = (float*)(w + off); off = alignup(off + (size_t)NROWS*NH*4);
  float* csb   = (float*)(w + off); off = alignup(off + (size_t)NBLK*128*4);
  float* dtvb  = (float*)(w + off); off = alignup(off + (size_t)NBLK*128*4);
  float* wjsb  = (float*)(w + off); off = alignup(off + (size_t)NBLK*128*4);
  float* rsb   = (float*)(w + off); off = alignup(off + (size_t)NROWS*4);
  float* dtot  = (float*)(w + off); off = alignup(off + (size_t)NBLK*4);
  float* lpart = (float*)(w + off); off = alignup(off + (size_t)BATCH*4096*4);
  // total ~233.5 MB
  u16* wT    = scr;
  u16* xn    = (u16*)((char*)scr + alignup((size_t)NPAD1*DM*2));
  u16* cstat = scr;

  build_x_kernel<<<NROWS, 256, 0, stream>>>(im8, from_rgb_w, from_rgb_b, s0, suffix,
                                            norm0_w, norm0_b, x);

  for (int i = 0; i < 4; i++) {
    ln_bf16_kernel<<<NROWS, 256, 0, stream>>>(x, ln_w + i*DM, ln_b + i*DM, xn);
    transp_bf16<<<dim3(NPAD1/32, DM/32), 256, 0, stream>>>(in_proj_w + (size_t)i*DM*DIP, wT, DM, DIP);
    gemm0<<<dim3(27, 66), 512, 0, stream>>>(xn, wT, zx, dt_bias + i*NH, dt);
    dtcs_kernel<<<NBLK, 128, 0, stream>>>(dt, A_log + i*NH, csb, dtvb, wjsb, dtot);
    convBC_kernel<<<BATCH*NCH, 256, 0, stream>>>(zx, conv_w + (size_t)i*(DI+2*DS)*4,
        conv_b + i*(DI+2*DS), Ccv, BcvT, Sraw);
    chunk_state_kernel<<<NBLK, 256, 0, stream>>>(zx, wjsb,
        conv_w + (size_t)i*(DI+2*DS)*4, conv_b + i*(DI+2*DS), BcvT, cstat);
    state_scan_kernel<<<BATCH*NH, 256, 0, stream>>>(cstat, dtot);
    chunk_output_kernel<<<NBLK, 512, 0, stream>>>(zx, csb, dtvb,
        conv_w + (size_t)i*(DI+2*DS)*4, conv_b + i*(DI+2*DS), Dvec + i*NH, Sraw, Ccv, cstat);
    rms_stats_kernel<<<NROWS, 256, 0, stream>>>(zx, rsb);
    transp_bf16<<<dim3(DM/32, DI/32), 256, 0, stream>>>(out_proj_w + (size_t)i*DI*DM, wT, DI, DM);
    gemm_out<<<dim3(6, 131), 256, 0, stream>>>(zx, rsb, gn_w + i*DI, wT, x);
  }

  head_kernel<<<BATCH*4096, 256, 0, stream>>>(x, to_rgb_w, to_rgb_b, im64, (float*)d_out, lpart);
  loss_reduce<<<1, 256, 0, stream>>>(lpart, (float*)d_out);
}

// Round 13
// 2129.528 us; speedup vs baseline: 1.0712x; 1.0712x over previous
//
#include <hip/hip_runtime.h>
#include <hip/hip_bf16.h>
#include <math.h>

// ---- problem constants ----
#define LTOT 4161
#define BATCH 4
#define NROWS (BATCH*LTOT)      // 16644
#define NPAD1 3456
#define DM 768
#define DI 1536
#define DIP 3352
#define ZLD 3328
#define NH 24
#define HD 64
#define DS 128
#define EPSF 1e-5f
#define CHK 128
#define NCH 33
#define NBLK (BATCH*NCH*NH)     // 3168
#define LDF 136
#define XLD 72
#define RLD 264

typedef __attribute__((ext_vector_type(8))) __bf16 bf16x8;
typedef __attribute__((ext_vector_type(4))) float f32x4;
typedef __attribute__((ext_vector_type(8))) short short8;
typedef __attribute__((ext_vector_type(4))) unsigned int u32x4;
typedef unsigned short u16;
typedef unsigned int u32;

static __device__ __forceinline__ u16 f2bf(float f){
  unsigned u = __builtin_bit_cast(unsigned, f);
  u += 0x7FFFu + ((u >> 16) & 1u);          // RNE
  return (u16)(u >> 16);
}
static __device__ __forceinline__ float bf2f(u16 v){
  return __builtin_bit_cast(float, ((unsigned)v) << 16);
}
static __device__ __forceinline__ float siluf(float v){ return v / (1.f + __expf(-v)); }

// bijective XCD-chunking remap (m204)
static __device__ __forceinline__ int xcd_swz(int orig, int nwg){
  int xcd = orig & 7;
  int idx = orig >> 3;
  int q = nwg >> 3, r = nwg & 7;
  int base = (xcd < r) ? xcd*(q + 1) : r*(q + 1) + (xcd - r)*q;
  return base + idx;
}

__device__ __forceinline__ float blockSum256(float v, float* sh){
  #pragma unroll
  for (int o = 32; o > 0; o >>= 1) v += __shfl_down(v, o);
  int w = threadIdx.x >> 6;
  if ((threadIdx.x & 63) == 0) sh[w] = v;
  __syncthreads();
  v = sh[0] + sh[1] + sh[2] + sh[3];
  __syncthreads();
  return v;
}

// ---- build x = LN0(concat(s0, h8, zm)) ----
__global__ __launch_bounds__(256)
void build_x_kernel(const float* __restrict__ im8, const float* __restrict__ frw,
                    const float* __restrict__ frb, const float* __restrict__ s0,
                    const float* __restrict__ suffix, const float* __restrict__ w,
                    const float* __restrict__ bb, float* __restrict__ x)
{
  int row = blockIdx.x;
  int b = row / LTOT, l = row % LTOT;
  int t = threadIdx.x;
  __shared__ float sh[4];
  float v[3];
  if (l == 0) {
    #pragma unroll
    for (int i = 0; i < 3; i++) v[i] = s0[t + i*256];
  } else if (l <= 64) {
    int p = l - 1;
    float r0 = im8[(b*64 + p)*3 + 0], r1 = im8[(b*64 + p)*3 + 1], r2 = im8[(b*64 + p)*3 + 2];
    #pragma unroll
    for (int i = 0; i < 3; i++) {
      int d = t + i*256;
      v[i] = r0*frw[d] + r1*frw[768 + d] + r2*frw[1536 + d] + frb[d];
    }
  } else {
    int j = l - 65;
    int p = ((j >> 9) << 3) | ((j & 63) >> 3);
    float r0 = im8[(b*64 + p)*3 + 0], r1 = im8[(b*64 + p)*3 + 1], r2 = im8[(b*64 + p)*3 + 2];
    #pragma unroll
    for (int i = 0; i < 3; i++) {
      int d = t + i*256;
      v[i] = r0*frw[d] + r1*frw[768 + d] + r2*frw[1536 + d] + frb[d] + suffix[(size_t)j*768 + d];
    }
  }
  float s = v[0] + v[1] + v[2];
  s = blockSum256(s, sh);
  float mu = s * (1.f/768.f);
  float q = 0;
  #pragma unroll
  for (int i = 0; i < 3; i++) { float d = v[i] - mu; q += d*d; }
  q = blockSum256(q, sh);
  float rs = rsqrtf(q * (1.f/768.f) + EPSF);
  float* xr = x + (size_t)row*DM;
  #pragma unroll
  for (int i = 0; i < 3; i++) {
    int d = t + i*256;
    xr[d] = (v[i] - mu)*rs*w[d] + bb[d];
  }
}

// ---- per-layer LN -> bf16 ; also zeroes ssq[row] for this layer's K3 accumulation ----
__global__ __launch_bounds__(256)
void ln_bf16_kernel(const float* __restrict__ x, const float* __restrict__ w,
                    const float* __restrict__ bb, u16* __restrict__ out,
                    float* __restrict__ ssq)
{
  int row = blockIdx.x;
  int t = threadIdx.x;
  __shared__ float sh[4];
  const float* xr = x + (size_t)row*DM;
  float v[3];
  #pragma unroll
  for (int i = 0; i < 3; i++) v[i] = xr[t + i*256];
  if (t == 0) ssq[row] = 0.f;
  float s = v[0] + v[1] + v[2];
  s = blockSum256(s, sh);
  float mu = s * (1.f/768.f);
  float q = 0;
  #pragma unroll
  for (int i = 0; i < 3; i++) { float d = v[i] - mu; q += d*d; }
  q = blockSum256(q, sh);
  float rs = rsqrtf(q * (1.f/768.f) + EPSF);
  u16* orow = out + (size_t)row*DM;
  #pragma unroll
  for (int i = 0; i < 3; i++) {
    int d = t + i*256;
    orow[d] = f2bf((v[i] - mu)*rs*w[d] + bb[d]);
  }
}

// ---- transpose + f32->bf16 ----
__global__ __launch_bounds__(256)
void transp_bf16(const float* __restrict__ in, u16* __restrict__ out, int K, int N)
{
  __shared__ float tl[32][33];
  int tx = threadIdx.x & 31, ty = threadIdx.x >> 5;
  int n0 = blockIdx.x * 32, k0 = blockIdx.y * 32;
  #pragma unroll
  for (int r = 0; r < 4; r++) {
    int k = k0 + ty + r*8, n = n0 + tx;
    tl[ty + r*8][tx] = (n < N) ? in[(size_t)k*N + n] : 0.f;
  }
  __syncthreads();
  #pragma unroll
  for (int r = 0; r < 4; r++) {
    int n = n0 + ty + r*8, k = k0 + tx;
    out[(size_t)n*K + k] = f2bf(tl[tx][ty + r*8]);
  }
}

#define LD8(p) (*(const short8*)(p))

// ---- GEMM0: zx = xn @ Wi ; reg-staged, BK=32, DOUBLE-BUFFERED (R10 proven config) ----
__global__ __launch_bounds__(256)
void gemm0(const u16* __restrict__ A, const u16* __restrict__ BT,
           u16* __restrict__ zxO, const float* __restrict__ dtbias,
           float* __restrict__ dtO)
{
  __shared__ __align__(16) u16 As[2][128*40];
  __shared__ __align__(16) u16 Bs[2][128*40];
  const int t = threadIdx.x;
  const int nid = xcd_swz(blockIdx.y*27 + blockIdx.x, 27*131);
  const int bm = nid / 27, bn = nid % 27;
  const int lane = t & 63, wave = t >> 6;
  const int wr = wave >> 1, wc = wave & 1;
  const int r16 = lane & 15, kb = lane >> 4;

  const int m = t >> 1, half = t & 1;
  const int grow = bm*128 + m;
  const bool valid = grow < NROWS;
  const u16* gA = A + (size_t)(valid ? grow : 0)*DM + half*16;
  const u16* gB = BT + (size_t)(bn*128 + m)*DM + half*16;
  const int wofs = m*40 + half*16;

  short8 a0 = {}, a1 = {}, b0, b1;
  b0 = LD8(gB); b1 = LD8(gB + 8);
  if (valid) { a0 = LD8(gA); a1 = LD8(gA + 8); }
  *(short8*)&As[0][wofs] = a0; *(short8*)&As[0][wofs + 8] = a1;
  *(short8*)&Bs[0][wofs] = b0; *(short8*)&Bs[0][wofs + 8] = b1;
  __syncthreads();

  f32x4 acc[4][4] = {};
  int p = 0;
  for (int kt = 0; kt < DM; kt += 32) {
    const bool more = (kt + 32 < DM);
    if (more) {
      b0 = LD8(gB + kt + 32); b1 = LD8(gB + kt + 40);
      if (valid) { a0 = LD8(gA + kt + 32); a1 = LD8(gA + kt + 40); }
    }
    bf16x8 af[4], bfr[4];
    #pragma unroll
    for (int i = 0; i < 4; i++) af[i]  = *(const bf16x8*)&As[p][(wr*64 + i*16 + r16)*40 + kb*8];
    #pragma unroll
    for (int i = 0; i < 4; i++) bfr[i] = *(const bf16x8*)&Bs[p][(wc*64 + i*16 + r16)*40 + kb*8];
    #pragma unroll
    for (int i = 0; i < 4; i++)
      #pragma unroll
      for (int j = 0; j < 4; j++)
        acc[i][j] = __builtin_amdgcn_mfma_f32_16x16x32_bf16(af[i], bfr[j], acc[i][j], 0, 0, 0);
    if (more) {
      *(short8*)&As[p^1][wofs] = a0; *(short8*)&As[p^1][wofs + 8] = a1;
      *(short8*)&Bs[p^1][wofs] = b0; *(short8*)&Bs[p^1][wofs + 8] = b1;
    }
    __syncthreads();
    p ^= 1;
  }
  const int rbase = bm*128 + wr*64, cbase = bn*128 + wc*64;
  #pragma unroll
  for (int i = 0; i < 4; i++) {
    #pragma unroll
    for (int j = 0; j < 4; j++) {
      int col = cbase + j*16 + r16;
      #pragma unroll
      for (int e = 0; e < 4; e++) {
        int row = rbase + i*16 + kb*4 + e;
        if (row < NROWS) {
          float v = acc[i][j][e];
          if (col < ZLD) {
            zxO[(size_t)row*ZLD + col] = f2bf(v);
          } else if (col < DIP) {
            int hh = col - ZLD;
            float d = v + dtbias[hh];
            d = (d > 20.f) ? d : log1pf(expf(d));
            dtO[(size_t)row*NH + hh] = d;
          }
        }
      }
    }
  }
}

// ---- GEMM1: x += rmsnorm-scaled gated zx @ Wo ; rs from ssq; BK=32 dbuf ----
__global__ __launch_bounds__(256)
void gemm_out(const u16* __restrict__ A, const float* __restrict__ ssq,
              const float* __restrict__ gw, const u16* __restrict__ BT,
              float* __restrict__ X)
{
  __shared__ __align__(16) u16 As[2][128*40];
  __shared__ __align__(16) u16 Bs[2][128*40];
  __shared__ float gwl[DI];
  const int t = threadIdx.x;
  const int nid = xcd_swz(blockIdx.y*6 + blockIdx.x, 6*131);
  const int bm = nid / 6, bn = nid % 6;
  const int lane = t & 63, wave = t >> 6;
  const int wr = wave >> 1, wc = wave & 1;
  const int r16 = lane & 15, kb = lane >> 4;

  for (int i = t; i < DI; i += 256) gwl[i] = gw[i];

  const int m = t >> 1, half = t & 1;
  const int grow = bm*128 + m;
  const bool valid = grow < NROWS;
  const float rs = valid ? rsqrtf(ssq[grow] * (1.f/1536.f) + EPSF) : 0.f;
  const u16* gA = A + (size_t)(valid ? grow : 0)*ZLD + half*16;
  const u16* gB = BT + (size_t)(bn*128 + m)*DI + half*16;
  const int wofs = m*40 + half*16;

  short8 ra0 = {}, ra1 = {}, b0, b1;
  b0 = LD8(gB); b1 = LD8(gB + 8);
  if (valid) { ra0 = LD8(gA); ra1 = LD8(gA + 8); }
  __syncthreads();                       // gwl visible
  {
    const int c0 = half*16;
    short8 ta0, ta1;
    #pragma unroll
    for (int j = 0; j < 8; j++) ta0[j] = (short)f2bf(bf2f((u16)ra0[j]) * rs * gwl[c0 + j]);
    #pragma unroll
    for (int j = 0; j < 8; j++) ta1[j] = (short)f2bf(bf2f((u16)ra1[j]) * rs * gwl[c0 + 8 + j]);
    *(short8*)&As[0][wofs] = ta0; *(short8*)&As[0][wofs + 8] = ta1;
    *(short8*)&Bs[0][wofs] = b0;  *(short8*)&Bs[0][wofs + 8] = b1;
  }
  __syncthreads();

  f32x4 acc[4][4] = {};
  int p = 0;
  for (int kt = 0; kt < DI; kt += 32) {
    const bool more = (kt + 32 < DI);
    if (more) {
      b0 = LD8(gB + kt + 32); b1 = LD8(gB + kt + 40);
      if (valid) { ra0 = LD8(gA + kt + 32); ra1 = LD8(gA + kt + 40); }
    }
    bf16x8 af[4], bfr[4];
    #pragma unroll
    for (int i = 0; i < 4; i++) af[i]  = *(const bf16x8*)&As[p][(wr*64 + i*16 + r16)*40 + kb*8];
    #pragma unroll
    for (int i = 0; i < 4; i++) bfr[i] = *(const bf16x8*)&Bs[p][(wc*64 + i*16 + r16)*40 + kb*8];
    #pragma unroll
    for (int i = 0; i < 4; i++)
      #pragma unroll
      for (int j = 0; j < 4; j++)
        acc[i][j] = __builtin_amdgcn_mfma_f32_16x16x32_bf16(af[i], bfr[j], acc[i][j], 0, 0, 0);
    if (more) {
      const int c0 = kt + 32 + half*16;
      short8 ta0, ta1;
      #pragma unroll
      for (int j = 0; j < 8; j++) ta0[j] = (short)f2bf(bf2f((u16)ra0[j]) * rs * gwl[c0 + j]);
      #pragma unroll
      for (int j = 0; j < 8; j++) ta1[j] = (short)f2bf(bf2f((u16)ra1[j]) * rs * gwl[c0 + 8 + j]);
      *(short8*)&As[p^1][wofs] = ta0; *(short8*)&As[p^1][wofs + 8] = ta1;
      *(short8*)&Bs[p^1][wofs] = b0;  *(short8*)&Bs[p^1][wofs + 8] = b1;
    }
    __syncthreads();
    p ^= 1;
  }
  const int rbase = bm*128 + wr*64, cbase = bn*128 + wc*64;
  #pragma unroll
  for (int i = 0; i < 4; i++) {
    #pragma unroll
    for (int j = 0; j < 4; j++) {
      int col = cbase + j*16 + r16;
      #pragma unroll
      for (int e = 0; e < 4; e++) {
        int row = rbase + i*16 + kb*4 + e;
        if (row < NROWS) X[(size_t)row*DM + col] += acc[i][j][e];
      }
    }
  }
}

// ======================= chunked SSD =======================

// ---- dtcs: per (b,c,h) prefix sums & weights ----
__global__ __launch_bounds__(128)
void dtcs_kernel(const float* __restrict__ dt, const float* __restrict__ alog,
                 float* __restrict__ csb, float* __restrict__ dtvb,
                 float* __restrict__ wjsb, float* __restrict__ dtot)
{
  const int id = blockIdx.x;
  const int h = id % NH; const int c = (id / NH) % NCH; const int b = id / (NH*NCH);
  const int t = threadIdx.x;
  const int base = c*CHK;
  int rows = LTOT - base; if (rows > CHK) rows = CHK;
  __shared__ float cs[128];
  float dv = 0.f;
  if (t < rows) dv = dt[(size_t)(b*LTOT + base + t)*NH + h];
  const float aexp = __expf(alog[h]);
  cs[t] = -dv * aexp;
  __syncthreads();
  for (int off = 1; off < 128; off <<= 1) {
    float add = (t >= off) ? cs[t - off] : 0.f;
    __syncthreads();
    cs[t] += add;
    __syncthreads();
  }
  float csl = cs[127];
  size_t o = (size_t)id*128 + t;
  csb[o] = cs[t];
  dtvb[o] = dv;
  wjsb[o] = __expf(csl - cs[t]) * dv;
  if (t == 0) dtot[id] = __expf(csl);
}

// ---- conv B/C once per (b,chunk); ALSO computes Sraw = C @ B^T (head-independent) ----
__global__ __launch_bounds__(256)
void convBC_kernel(const u16* __restrict__ zx, const float* __restrict__ cw,
                   const float* __restrict__ cb, u16* __restrict__ Ccv,
                   u16* __restrict__ BcvT, u16* __restrict__ Sraw)
{
  const int bc = xcd_swz(blockIdx.x, BATCH*NCH);
  const int b = bc / NCH, c = bc % NCH;
  const int t = threadIdx.x;
  const int base = c*CHK;
  __shared__ __align__(16) u16 raw[131*RLD + 8];
  __shared__ __align__(16) u16 Bt[128*LDF];
  __shared__ __align__(16) u16 Ct[128*LDF];
  const u16* zb = zx + (size_t)(b*LTOT)*ZLD;

  #pragma unroll
  for (int rg = 0; rg < 17; rg++) {
    int idx = rg*256 + t;
    int r = idx >> 5, seg = idx & 31;
    if (r < 131) {
      int g = base - 3 + r;
      short8 v = {};
      if (g >= 0 && g < LTOT) v = LD8(zb + (size_t)g*ZLD + 3072 + seg*8);
      *(short8*)&raw[r*RLD + seg*8] = v;
    }
  }
  __syncthreads();
  {
    const int isC = t >> 7, n = t & 127;
    const int ch = 1536 + t;
    float w0 = cw[ch*4+0], w1 = cw[ch*4+1], w2 = cw[ch*4+2], w3 = cw[ch*4+3];
    float bias = cb[ch];
    float r0 = bf2f(raw[0*RLD + t]);
    float r1 = bf2f(raw[1*RLD + t]);
    float r2 = bf2f(raw[2*RLD + t]);
    u16* dstT = isC ? Ct : Bt;
    #pragma unroll 4
    for (int j = 0; j < 128; j++) {
      float r3 = bf2f(raw[(j + 3)*RLD + t]);
      float o = bias + w0*r0 + w1*r1 + w2*r2 + w3*r3;
      dstT[j*LDF + n] = f2bf(siluf(o));
      r0 = r1; r1 = r2; r2 = r3;
    }
  }
  __syncthreads();
  // write Ccv [l][n]
  #pragma unroll
  for (int rg = 0; rg < 8; rg++) {
    int idx = rg*256 + t;
    int r = idx >> 4, seg = idx & 15;
    int g = base + r;
    if (g < LTOT)
      *(short8*)(Ccv + (size_t)(b*LTOT + g)*128 + seg*8) = *(const short8*)&Ct[r*LDF + seg*8];
  }
  // write BcvT [n][j]
  u16* bT = BcvT + (size_t)bc*16384;
  #pragma unroll
  for (int rg = 0; rg < 8; rg++) {
    int idx = rg*256 + t;
    int n = idx >> 4, js = (idx & 15)*8;
    short8 v;
    #pragma unroll
    for (int k = 0; k < 8; k++) v[k] = (short)Bt[(js + k)*LDF + n];
    *(short8*)(bT + n*128 + js) = v;
  }
  // Sraw[i][j] = sum_n Ct[i][n]*Bt[j][n]
  {
    const int lane = t & 63, wave = t >> 6;
    const int r16 = lane & 15, kb = lane >> 4;
    f32x4 acc[2][8] = {};
    #pragma unroll
    for (int kt = 0; kt < 4; kt++) {
      bf16x8 af[2], bfr[8];
      #pragma unroll
      for (int m2 = 0; m2 < 2; m2++) af[m2] = *(const bf16x8*)&Ct[(wave*32 + m2*16 + r16)*LDF + kt*32 + kb*8];
      #pragma unroll
      for (int nj = 0; nj < 8; nj++) bfr[nj] = *(const bf16x8*)&Bt[(nj*16 + r16)*LDF + kt*32 + kb*8];
      #pragma unroll
      for (int m2 = 0; m2 < 2; m2++)
        #pragma unroll
        for (int nj = 0; nj < 8; nj++)
          acc[m2][nj] = __builtin_amdgcn_mfma_f32_16x16x32_bf16(af[m2], bfr[nj], acc[m2][nj], 0, 0, 0);
    }
    u16* sdst = Sraw + (size_t)bc*16384;
    #pragma unroll
    for (int m2 = 0; m2 < 2; m2++)
      #pragma unroll
      for (int nj = 0; nj < 8; nj++)
        #pragma unroll
        for (int e = 0; e < 4; e++) {
          int i = wave*32 + m2*16 + kb*4 + e;
          int j = nj*16 + r16;
          sdst[i*128 + j] = f2bf(acc[m2][nj][e]);
        }
  }
}

// ---- K1: per-chunk state ----
__global__ __launch_bounds__(256)
void chunk_state_kernel(const u16* __restrict__ zx, const float* __restrict__ wjsb,
                        const float* __restrict__ cw, const float* __restrict__ cb,
                        const u16* __restrict__ BcvT, u16* __restrict__ cstat)
{
  const int id = xcd_swz(blockIdx.x, NBLK);
  const int h = id % NH; const int c = (id / NH) % NCH; const int b = id / (NH*NCH);
  const int t = threadIdx.x;
  const int base = c*CHK;

  __shared__ __align__(16) u16 Bbuf[128*LDF];
  __shared__ __align__(16) u16 xbuf[131*XLD + 8];
  __shared__ float wjs[128];

  const u16* zb = zx + (size_t)(b*LTOT)*ZLD;
  if (t < 128) wjs[t] = wjsb[(size_t)id*128 + t];
  {
    const u16* bT = BcvT + (size_t)(b*NCH + c)*16384;
    #pragma unroll
    for (int rg = 0; rg < 8; rg++) {
      int idx = rg*256 + t;
      int n = idx >> 4, js = (idx & 15)*8;
      *(short8*)&Bbuf[n*LDF + js] = LD8(bT + n*128 + js);
    }
  }
  #pragma unroll
  for (int rg = 0; rg < 5; rg++) {
    int r = rg*32 + (t >> 3);
    int seg = t & 7;
    if (r < 131) {
      int g = base - 3 + r;
      short8 v = {};
      if (g >= 0 && g < LTOT) v = LD8(zb + (size_t)g*ZLD + 1536 + h*HD + seg*8);
      *(short8*)&xbuf[r*XLD + seg*8] = v;
    }
  }
  __syncthreads();

  const int p_ = t & 63, jq = t >> 6;
  u32 pkx[16];
  {
    const int ch = h*HD + p_;
    float w0 = cw[ch*4+0], w1 = cw[ch*4+1], w2 = cw[ch*4+2], w3 = cw[ch*4+3];
    float bias = cb[ch];
    const int rb = jq*32;
    float r0 = bf2f(xbuf[(rb+0)*XLD + p_]);
    float r1 = bf2f(xbuf[(rb+1)*XLD + p_]);
    float r2 = bf2f(xbuf[(rb+2)*XLD + p_]);
    #pragma unroll
    for (int k2 = 0; k2 < 16; k2++) {
      float r3 = bf2f(xbuf[(rb + 2*k2 + 3)*XLD + p_]);
      float o0 = bias + w0*r0 + w1*r1 + w2*r2 + w3*r3;
      float r4 = bf2f(xbuf[(rb + 2*k2 + 4)*XLD + p_]);
      float o1 = bias + w0*r1 + w1*r2 + w2*r3 + w3*r4;
      float s0 = siluf(o0) * wjs[rb + 2*k2];
      float s1 = siluf(o1) * wjs[rb + 2*k2 + 1];
      pkx[k2] = (u32)f2bf(s0) | ((u32)f2bf(s1) << 16);
      r0 = r2; r1 = r3; r2 = r4;
    }
  }
  __syncthreads();
  #pragma unroll
  for (int q = 0; q < 4; q++) {
    u32x4 v; v[0] = pkx[q*4]; v[1] = pkx[q*4+1]; v[2] = pkx[q*4+2]; v[3] = pkx[q*4+3];
    *(u32x4*)&xbuf[p_*LDF + jq*32 + q*8] = v;
  }
  __syncthreads();

  const int lane = t & 63, wave = t >> 6;
  const int r16 = lane & 15, kb = lane >> 4;
  const int n0 = wave*32;
  f32x4 acc[4][2] = {};
  #pragma unroll
  for (int kt = 0; kt < 4; kt++) {
    bf16x8 af[4], bfr[2];
    #pragma unroll
    for (int m = 0; m < 4; m++) af[m] = *(const bf16x8*)&xbuf[(m*16 + r16)*LDF + kt*32 + kb*8];
    #pragma unroll
    for (int nn = 0; nn < 2; nn++) bfr[nn] = *(const bf16x8*)&Bbuf[(n0 + nn*16 + r16)*LDF + kt*32 + kb*8];
    #pragma unroll
    for (int m = 0; m < 4; m++)
      #pragma unroll
      for (int nn = 0; nn < 2; nn++)
        acc[m][nn] = __builtin_amdgcn_mfma_f32_16x16x32_bf16(af[m], bfr[nn], acc[m][nn], 0, 0, 0);
  }
  u16* dst = cstat + (size_t)id*64*128;
  #pragma unroll
  for (int m = 0; m < 4; m++)
    #pragma unroll
    for (int nn = 0; nn < 2; nn++)
      #pragma unroll
      for (int e = 0; e < 4; e++) {
        int p = m*16 + kb*4 + e;
        int n = n0 + nn*16 + r16;
        dst[p*128 + n] = f2bf(acc[m][nn][e]);
      }
}

// ---- K2: inter-chunk scan ----
__global__ __launch_bounds__(256)
void state_scan_kernel(u16* __restrict__ cstat, const float* __restrict__ dtot)
{
  const int b = blockIdx.x / NH, h = blockIdx.x % NH;
  const int t = threadIdx.x;
  float run[32];
  #pragma unroll
  for (int k = 0; k < 32; k++) run[k] = 0.f;
  size_t id0 = (size_t)(b*NCH)*NH + h;
  short8 cur[4];
  {
    const u16* s0 = cstat + id0*8192 + t*32;
    #pragma unroll
    for (int q = 0; q < 4; q++) cur[q] = LD8(s0 + q*8);
  }
  float d = dtot[id0];
  for (int c = 0; c < NCH; ++c) {
    size_t id = (size_t)(b*NCH + c)*NH + h;
    u16* slab = cstat + id*8192 + t*32;
    short8 nxt[4] = {}; float nd = 0.f;
    if (c + 1 < NCH) {
      const u16* sn = slab + (size_t)NH*8192;
      #pragma unroll
      for (int q = 0; q < 4; q++) nxt[q] = LD8(sn + q*8);
      nd = dtot[id + NH];
    }
    short8 out[4];
    #pragma unroll
    for (int q = 0; q < 4; q++)
      #pragma unroll
      for (int k = 0; k < 8; k++) {
        int idx = q*8 + k;
        float csv = bf2f((u16)cur[q][k]);
        out[q][k] = (short)f2bf(run[idx]);
        run[idx] = run[idx]*d + csv;
      }
    #pragma unroll
    for (int q = 0; q < 4; q++) *(short8*)(slab + q*8) = out[q];
    #pragma unroll
    for (int q = 0; q < 4; q++) cur[q] = nxt[q];
    d = nd;
  }
}

// ---- K3: per-chunk output; masked staging of precomputed Sraw; fused ssq ----
__global__ __launch_bounds__(512, 4)
void chunk_output_kernel(u16* __restrict__ zx, const float* __restrict__ csb,
                         const float* __restrict__ dtvb, const float* __restrict__ cw,
                         const float* __restrict__ cb, const float* __restrict__ Dvec,
                         const u16* __restrict__ Sraw, const u16* __restrict__ Ccv,
                         const u16* __restrict__ cstat, float* __restrict__ ssq)
{
  const int id = xcd_swz(blockIdx.x, NBLK);
  const int h = id % NH; const int c = (id / NH) % NCH; const int b = id / (NH*NCH);
  const int t = threadIdx.x;
  const int base = c*CHK;
  int rows = LTOT - base; if (rows > CHK) rows = CHK;

  __shared__ __align__(16) u16 Bc[128*LDF];       // P[i][j]
  __shared__ __align__(16) u16 stT[64*LDF];       // state_before [p][n]
  __shared__ __align__(16) u16 xbuf[131*XLD + 8]; // raw x -> xc[p][j]
  __shared__ float dtv[128];
  __shared__ float cs[128];

  const u16* zb = zx + (size_t)(b*LTOT)*ZLD;
  const size_t crow0 = (size_t)(b*LTOT)*128;
  if (t < 128) {
    cs[t]  = csb[(size_t)id*128 + t];
    dtv[t] = dtvb[(size_t)id*128 + t];
  }
  {
    const u16* slab = cstat + (size_t)id*8192;
    int p = t >> 3, nb = (t & 7)*16;
    *(short8*)&stT[p*LDF + nb]     = LD8(slab + p*128 + nb);
    *(short8*)&stT[p*LDF + nb + 8] = LD8(slab + p*128 + nb + 8);
  }
  #pragma unroll
  for (int rg = 0; rg < 3; rg++) {
    int r = rg*64 + (t >> 3);
    int seg = t & 7;
    if (r < 131) {
      int g = base - 3 + r;
      short8 v = {};
      if (g >= 0 && g < LTOT) v = LD8(zb + (size_t)g*ZLD + 1536 + h*HD + seg*8);
      *(short8*)&xbuf[r*XLD + seg*8] = v;
    }
  }
  __syncthreads();

  // x conv -> regs  ||  P staging: load Sraw, apply per-head mask, write LDS
  const int p_ = t & 63, jq = t >> 6;
  u32 pkx[8];
  {
    const int ch = h*HD + p_;
    float w0 = cw[ch*4+0], w1 = cw[ch*4+1], w2 = cw[ch*4+2], w3 = cw[ch*4+3];
    float bias = cb[ch];
    const int rb = jq*16;
    float r0 = bf2f(xbuf[(rb+0)*XLD + p_]);
    float r1 = bf2f(xbuf[(rb+1)*XLD + p_]);
    float r2 = bf2f(xbuf[(rb+2)*XLD + p_]);
    #pragma unroll
    for (int k2 = 0; k2 < 8; k2++) {
      float r3 = bf2f(xbuf[(rb + 2*k2 + 3)*XLD + p_]);
      float o0 = bias + w0*r0 + w1*r1 + w2*r2 + w3*r3;
      float r4 = bf2f(xbuf[(rb + 2*k2 + 4)*XLD + p_]);
      float o1 = bias + w0*r1 + w1*r2 + w2*r3 + w3*r4;
      int j0 = rb + 2*k2;
      u32 lo = (j0     < rows) ? (u32)f2bf(siluf(o0)) : 0u;
      u32 hi = (j0 + 1 < rows) ? (u32)f2bf(siluf(o1)) : 0u;
      pkx[k2] = lo | (hi << 16);
      r0 = r2; r1 = r3; r2 = r4;
    }
  }
  {
    const u16* sS = Sraw + (size_t)(b*NCH + c)*16384;
    #pragma unroll
    for (int q = 0; q < 4; q++) {
      int idx = q*512 + t;
      int i = idx >> 4, seg = (idx & 15)*8;
      short8 s = LD8(sS + i*128 + seg);
      float csi = cs[i];
      short8 o;
      #pragma unroll
      for (int k = 0; k < 8; k++) {
        int j = seg + k;
        float f = 0.f;
        if (j <= i && i < rows) f = __expf(csi - cs[j]) * dtv[j];
        o[k] = (short)f2bf(bf2f((u16)s[k]) * f);
      }
      *(short8*)&Bc[i*LDF + seg] = o;
    }
  }
  __syncthreads();
  {
    u32x4 v0; v0[0] = pkx[0]; v0[1] = pkx[1]; v0[2] = pkx[2]; v0[3] = pkx[3];
    u32x4 v1; v1[0] = pkx[4]; v1[1] = pkx[5]; v1[2] = pkx[6]; v1[3] = pkx[7];
    *(u32x4*)&xbuf[p_*LDF + jq*16]     = v0;
    *(u32x4*)&xbuf[p_*LDF + jq*16 + 8] = v1;
  }
  __syncthreads();

  const int lane = t & 63, wave = t >> 6;
  const int r16 = lane & 15, kb = lane >> 4;

  // Phase B: Y1 = P @ xc^T ; Phase C: Y2 = C @ st^T (C direct from global) ; epilogue
  {
    const int iq = wave;
    bf16x8 cF[4];
    {
      int i = iq*16 + r16;
      int g = base + i; if (g >= LTOT) g = base;
      #pragma unroll
      for (int kt = 0; kt < 4; kt++)
        cF[kt] = *(const bf16x8*)(Ccv + crow0 + (size_t)g*128 + kt*32 + kb*8);
    }
    f32x4 accY[4] = {};
    #pragma unroll
    for (int kt = 0; kt < 4; kt++) {
      bf16x8 af = *(const bf16x8*)&Bc[(iq*16 + r16)*LDF + kt*32 + kb*8];
      #pragma unroll
      for (int n = 0; n < 4; n++) {
        bf16x8 bfr = *(const bf16x8*)&xbuf[(n*16 + r16)*LDF + kt*32 + kb*8];
        accY[n] = __builtin_amdgcn_mfma_f32_16x16x32_bf16(af, bfr, accY[n], 0, 0, 0);
      }
    }
    f32x4 accS[4] = {};
    #pragma unroll
    for (int kt = 0; kt < 4; kt++) {
      #pragma unroll
      for (int n = 0; n < 4; n++) {
        bf16x8 bfr = *(const bf16x8*)&stT[(n*16 + r16)*LDF + kt*32 + kb*8];
        accS[n] = __builtin_amdgcn_mfma_f32_16x16x32_bf16(cF[kt], bfr, accS[n], 0, 0, 0);
      }
    }
    const float dcoef = Dvec[h];
    #pragma unroll
    for (int e = 0; e < 4; e++) {
      int i = iq*16 + kb*4 + e;
      if (i < rows) {
        float sc = __expf(cs[i]);
        size_t orow = (size_t)(b*LTOT + base + i)*ZLD + h*HD;
        float g2 = 0.f;
        #pragma unroll
        for (int n = 0; n < 4; n++) {
          int p = n*16 + r16;
          float xv = bf2f(xbuf[p*LDF + i]);
          float yv = accY[n][e] + sc*accS[n][e] + dcoef*xv;
          float gv = yv * siluf(bf2f(zx[orow + p]));
          zx[orow + p] = f2bf(gv);
          g2 += gv*gv;
        }
        // reduce over the 16-lane r16 group (same kb,e -> same row)
        g2 += __shfl_xor(g2, 1);
        g2 += __shfl_xor(g2, 2);
        g2 += __shfl_xor(g2, 4);
        g2 += __shfl_xor(g2, 8);
        if (r16 == 0) atomicAdd(&ssq[b*LTOT + base + i], g2);
      }
    }
  }
}

// ---- head ----
__global__ __launch_bounds__(256)
void head_kernel(const float* __restrict__ x, const float* __restrict__ tw,
                 const float* __restrict__ tb, const float* __restrict__ im64,
                 float* __restrict__ out, float* __restrict__ partial)
{
  int bj = blockIdx.x;
  int b = bj >> 12, j = bj & 4095;
  int row = b*LTOT + 65 + j;
  const float* xr = x + (size_t)row*DM;
  int t = threadIdx.x;
  float p0 = 0, p1 = 0, p2 = 0;
  for (int k = t; k < 768; k += 256) {
    float xv = xr[k];
    p0 += xv*tw[k*3 + 0]; p1 += xv*tw[k*3 + 1]; p2 += xv*tw[k*3 + 2];
  }
  __shared__ float sh[4];
  p0 = blockSum256(p0, sh);
  p1 = blockSum256(p1, sh);
  p2 = blockSum256(p2, sh);
  if (t == 0) {
    float y0 = p0 + tb[0], y1 = p1 + tb[1], y2 = p2 + tb[2];
    size_t o = (size_t)bj*3;
    out[o] = y0; out[o + 1] = y1; out[o + 2] = y2;
    float d0 = y0 - im64[o], d1 = y1 - im64[o + 1], d2 = y2 - im64[o + 2];
    partial[bj] = d0*d0 + d1*d1 + d2*d2;
  }
}

__global__ __launch_bounds__(256)
void loss_reduce(const float* __restrict__ partial, float* __restrict__ out)
{
  int t = threadIdx.x;
  float s = 0.f;
  for (int i = t; i < BATCH*4096; i += 256) s += partial[i];
  __shared__ float sh[4];
  s = blockSum256(s, sh);
  if (t == 0) out[49152] = s * (1.f/49152.f);
}

// ---- launcher ----
static inline size_t alignup(size_t v){ return (v + 255) & ~(size_t)255; }

extern "C" void kernel_launch(void* const* d_in, const int* in_sizes, int n_in,
                              void* d_out, int out_size, void* d_ws, size_t ws_size,
                              hipStream_t stream)
{
  const float* im8        = (const float*)d_in[0];
  const float* im64       = (const float*)d_in[1];
  const float* from_rgb_w = (const float*)d_in[2];
  const float* from_rgb_b = (const float*)d_in[3];
  const float* to_rgb_w   = (const float*)d_in[4];
  const float* to_rgb_b   = (const float*)d_in[5];
  const float* s0         = (const float*)d_in[6];
  const float* suffix     = (const float*)d_in[7];
  const float* norm0_w    = (const float*)d_in[8];
  const float* norm0_b    = (const float*)d_in[9];
  const float* ln_w       = (const float*)d_in[10];
  const float* ln_b       = (const float*)d_in[11];
  const float* in_proj_w  = (const float*)d_in[12];
  const float* conv_w     = (const float*)d_in[13];
  const float* conv_b     = (const float*)d_in[14];
  const float* dt_bias    = (const float*)d_in[15];
  const float* A_log      = (const float*)d_in[16];
  const float* Dvec       = (const float*)d_in[17];
  const float* gn_w       = (const float*)d_in[18];
  const float* out_proj_w = (const float*)d_in[19];

  char* w = (char*)d_ws;
  size_t off = 0;
  float* x     = (float*)(w + off); off = alignup(off + (size_t)NROWS*DM*4);
  u16*   zx    = (u16*)  (w + off); off = alignup(off + (size_t)NROWS*ZLD*2);
  u16*   scr   = (u16*)  (w + off); off = alignup(off + (size_t)NBLK*64*128*2);
  u16*   Sraw  = (u16*)  (w + off); off = alignup(off + (size_t)BATCH*NCH*16384*2);
  u16*   Ccv   = (u16*)  (w + off); off = alignup(off + (size_t)NROWS*128*2);
  u16*   BcvT  = (u16*)  (w + off); off = alignup(off + (size_t)BATCH*NCH*16384*2);
  float* dt    = (float*)(w + off); off = alignup(off + (size_t)NROWS*NH*4);
  float* csb   = (float*)(w + off); off = alignup(off + (size_t)NBLK*128*4);
  float* dtvb  = (float*)(w + off); off = alignup(off + (size_t)NBLK*128*4);
  float* wjsb  = (float*)(w + off); off = alignup(off + (size_t)NBLK*128*4);
  float* ssq   = (float*)(w + off); off = alignup(off + (size_t)NROWS*4);
  float* dtot  = (float*)(w + off); off = alignup(off + (size_t)NBLK*4);
  float* lpart = (float*)(w + off); off = alignup(off + (size_t)BATCH*4096*4);
  // total ~233.5 MB
  u16* wT    = scr;
  u16* xn    = (u16*)((char*)scr + alignup((size_t)NPAD1*DM*2));
  u16* cstat = scr;

  build_x_kernel<<<NROWS, 256, 0, stream>>>(im8, from_rgb_w, from_rgb_b, s0, suffix,
                                            norm0_w, norm0_b, x);

  for (int i = 0; i < 4; i++) {
    ln_bf16_kernel<<<NROWS, 256, 0, stream>>>(x, ln_w + i*DM, ln_b + i*DM, xn, ssq);
    transp_bf16<<<dim3(NPAD1/32, DM/32), 256, 0, stream>>>(in_proj_w + (size_t)i*DM*DIP, wT, DM, DIP);
    gemm0<<<dim3(27, 131), 256, 0, stream>>>(xn, wT, zx, dt_bias + i*NH, dt);
    dtcs_kernel<<<NBLK, 128, 0, stream>>>(dt, A_log + i*NH, csb, dtvb, wjsb, dtot);
    convBC_kernel<<<BATCH*NCH, 256, 0, stream>>>(zx, conv_w + (size_t)i*(DI+2*DS)*4,
        conv_b + i*(DI+2*DS), Ccv, BcvT, Sraw);
    chunk_state_kernel<<<NBLK, 256, 0, stream>>>(zx, wjsb,
        conv_w + (size_t)i*(DI+2*DS)*4, conv_b + i*(DI+2*DS), BcvT, cstat);
    state_scan_kernel<<<BATCH*NH, 256, 0, stream>>>(cstat, dtot);
    chunk_output_kernel<<<NBLK, 512, 0, stream>>>(zx, csb, dtvb,
        conv_w + (size_t)i*(DI+2*DS)*4, conv_b + i*(DI+2*DS), Dvec + i*NH, Sraw, Ccv, cstat, ssq);
    transp_bf16<<<dim3(DM/32, DI/32), 256, 0, stream>>>(out_proj_w + (size_t)i*DI*DM, wT, DI, DM);
    gemm_out<<<dim3(6, 131), 256, 0, stream>>>(zx, ssq, gn_w + i*DI, wT, x);
  }

  head_kernel<<<BATCH*4096, 256, 0, stream>>>(x, to_rgb_w, to_rgb_b, im64, (float*)d_out, lpart);
  loss_reduce<<<1, 256, 0, stream>>>(lpart, (float*)d_out);
}

// Round 14
// 1986.129 us; speedup vs baseline: 1.1486x; 1.0722x over previous
//
#include <hip/hip_runtime.h>
#include <hip/hip_bf16.h>
#include <math.h>

// ---- problem constants ----
#define LTOT 4161
#define BATCH 4
#define NROWS (BATCH*LTOT)      // 16644
#define NPAD1 3456
#define DM 768
#define DI 1536
#define DIP 3352
#define ZLD 3328
#define NH 24
#define HD 64
#define DS 128
#define EPSF 1e-5f
#define CHK 128
#define NCH 33
#define NBLK (BATCH*NCH*NH)     // 3168
#define LDF 136
#define XLD 72
#define RLD 264

typedef __attribute__((ext_vector_type(8))) __bf16 bf16x8;
typedef __attribute__((ext_vector_type(4))) float f32x4;
typedef __attribute__((ext_vector_type(8))) short short8;
typedef __attribute__((ext_vector_type(4))) unsigned int u32x4;
typedef unsigned short u16;
typedef unsigned int u32;

static __device__ __forceinline__ u16 f2bf(float f){
  unsigned u = __builtin_bit_cast(unsigned, f);
  u += 0x7FFFu + ((u >> 16) & 1u);          // RNE
  return (u16)(u >> 16);
}
static __device__ __forceinline__ float bf2f(u16 v){
  return __builtin_bit_cast(float, ((unsigned)v) << 16);
}
static __device__ __forceinline__ float siluf(float v){ return v / (1.f + __expf(-v)); }

// bijective XCD-chunking remap (m204)
static __device__ __forceinline__ int xcd_swz(int orig, int nwg){
  int xcd = orig & 7;
  int idx = orig >> 3;
  int q = nwg >> 3, r = nwg & 7;
  int base = (xcd < r) ? xcd*(q + 1) : r*(q + 1) + (xcd - r)*q;
  return base + idx;
}

__device__ __forceinline__ float blockSum256(float v, float* sh){
  #pragma unroll
  for (int o = 32; o > 0; o >>= 1) v += __shfl_down(v, o);
  int w = threadIdx.x >> 6;
  if ((threadIdx.x & 63) == 0) sh[w] = v;
  __syncthreads();
  v = sh[0] + sh[1] + sh[2] + sh[3];
  __syncthreads();
  return v;
}

// ---- build x = LN0(concat(s0, h8, zm)) ----
__global__ __launch_bounds__(256)
void build_x_kernel(const float* __restrict__ im8, const float* __restrict__ frw,
                    const float* __restrict__ frb, const float* __restrict__ s0,
                    const float* __restrict__ suffix, const float* __restrict__ w,
                    const float* __restrict__ bb, float* __restrict__ x)
{
  int row = blockIdx.x;
  int b = row / LTOT, l = row % LTOT;
  int t = threadIdx.x;
  __shared__ float sh[4];
  float v[3];
  if (l == 0) {
    #pragma unroll
    for (int i = 0; i < 3; i++) v[i] = s0[t + i*256];
  } else if (l <= 64) {
    int p = l - 1;
    float r0 = im8[(b*64 + p)*3 + 0], r1 = im8[(b*64 + p)*3 + 1], r2 = im8[(b*64 + p)*3 + 2];
    #pragma unroll
    for (int i = 0; i < 3; i++) {
      int d = t + i*256;
      v[i] = r0*frw[d] + r1*frw[768 + d] + r2*frw[1536 + d] + frb[d];
    }
  } else {
    int j = l - 65;
    int p = ((j >> 9) << 3) | ((j & 63) >> 3);
    float r0 = im8[(b*64 + p)*3 + 0], r1 = im8[(b*64 + p)*3 + 1], r2 = im8[(b*64 + p)*3 + 2];
    #pragma unroll
    for (int i = 0; i < 3; i++) {
      int d = t + i*256;
      v[i] = r0*frw[d] + r1*frw[768 + d] + r2*frw[1536 + d] + frb[d] + suffix[(size_t)j*768 + d];
    }
  }
  float s = v[0] + v[1] + v[2];
  s = blockSum256(s, sh);
  float mu = s * (1.f/768.f);
  float q = 0;
  #pragma unroll
  for (int i = 0; i < 3; i++) { float d = v[i] - mu; q += d*d; }
  q = blockSum256(q, sh);
  float rs = rsqrtf(q * (1.f/768.f) + EPSF);
  float* xr = x + (size_t)row*DM;
  #pragma unroll
  for (int i = 0; i < 3; i++) {
    int d = t + i*256;
    xr[d] = (v[i] - mu)*rs*w[d] + bb[d];
  }
}

// ---- per-layer LN -> bf16 ; also zeroes ssq[row] ----
__global__ __launch_bounds__(256)
void ln_bf16_kernel(const float* __restrict__ x, const float* __restrict__ w,
                    const float* __restrict__ bb, u16* __restrict__ out,
                    float* __restrict__ ssq)
{
  int row = blockIdx.x;
  int t = threadIdx.x;
  __shared__ float sh[4];
  const float* xr = x + (size_t)row*DM;
  float v[3];
  #pragma unroll
  for (int i = 0; i < 3; i++) v[i] = xr[t + i*256];
  if (t == 0) ssq[row] = 0.f;
  float s = v[0] + v[1] + v[2];
  s = blockSum256(s, sh);
  float mu = s * (1.f/768.f);
  float q = 0;
  #pragma unroll
  for (int i = 0; i < 3; i++) { float d = v[i] - mu; q += d*d; }
  q = blockSum256(q, sh);
  float rs = rsqrtf(q * (1.f/768.f) + EPSF);
  u16* orow = out + (size_t)row*DM;
  #pragma unroll
  for (int i = 0; i < 3; i++) {
    int d = t + i*256;
    orow[d] = f2bf((v[i] - mu)*rs*w[d] + bb[d]);
  }
}

// ---- transpose + f32->bf16 ----
__global__ __launch_bounds__(256)
void transp_bf16(const float* __restrict__ in, u16* __restrict__ out, int K, int N)
{
  __shared__ float tl[32][33];
  int tx = threadIdx.x & 31, ty = threadIdx.x >> 5;
  int n0 = blockIdx.x * 32, k0 = blockIdx.y * 32;
  #pragma unroll
  for (int r = 0; r < 4; r++) {
    int k = k0 + ty + r*8, n = n0 + tx;
    tl[ty + r*8][tx] = (n < N) ? in[(size_t)k*N + n] : 0.f;
  }
  __syncthreads();
  #pragma unroll
  for (int r = 0; r < 4; r++) {
    int n = n0 + ty + r*8, k = k0 + tx;
    out[(size_t)n*K + k] = f2bf(tl[tx][ty + r*8]);
  }
}

#define LD8(p) (*(const short8*)(p))

// ---- GEMM0: zx = xn @ Wi ; reg-staged, BK=32, DOUBLE-BUFFERED ----
__global__ __launch_bounds__(256)
void gemm0(const u16* __restrict__ A, const u16* __restrict__ BT,
           u16* __restrict__ zxO, const float* __restrict__ dtbias,
           float* __restrict__ dtO)
{
  __shared__ __align__(16) u16 As[2][128*40];
  __shared__ __align__(16) u16 Bs[2][128*40];
  const int t = threadIdx.x;
  const int nid = xcd_swz(blockIdx.y*27 + blockIdx.x, 27*131);
  const int bm = nid / 27, bn = nid % 27;
  const int lane = t & 63, wave = t >> 6;
  const int wr = wave >> 1, wc = wave & 1;
  const int r16 = lane & 15, kb = lane >> 4;

  const int m = t >> 1, half = t & 1;
  const int grow = bm*128 + m;
  const bool valid = grow < NROWS;
  const u16* gA = A + (size_t)(valid ? grow : 0)*DM + half*16;
  const u16* gB = BT + (size_t)(bn*128 + m)*DM + half*16;
  const int wofs = m*40 + half*16;

  short8 a0 = {}, a1 = {}, b0, b1;
  b0 = LD8(gB); b1 = LD8(gB + 8);
  if (valid) { a0 = LD8(gA); a1 = LD8(gA + 8); }
  *(short8*)&As[0][wofs] = a0; *(short8*)&As[0][wofs + 8] = a1;
  *(short8*)&Bs[0][wofs] = b0; *(short8*)&Bs[0][wofs + 8] = b1;
  __syncthreads();

  f32x4 acc[4][4] = {};
  int p = 0;
  for (int kt = 0; kt < DM; kt += 32) {
    const bool more = (kt + 32 < DM);
    if (more) {
      b0 = LD8(gB + kt + 32); b1 = LD8(gB + kt + 40);
      if (valid) { a0 = LD8(gA + kt + 32); a1 = LD8(gA + kt + 40); }
    }
    bf16x8 af[4], bfr[4];
    #pragma unroll
    for (int i = 0; i < 4; i++) af[i]  = *(const bf16x8*)&As[p][(wr*64 + i*16 + r16)*40 + kb*8];
    #pragma unroll
    for (int i = 0; i < 4; i++) bfr[i] = *(const bf16x8*)&Bs[p][(wc*64 + i*16 + r16)*40 + kb*8];
    #pragma unroll
    for (int i = 0; i < 4; i++)
      #pragma unroll
      for (int j = 0; j < 4; j++)
        acc[i][j] = __builtin_amdgcn_mfma_f32_16x16x32_bf16(af[i], bfr[j], acc[i][j], 0, 0, 0);
    if (more) {
      *(short8*)&As[p^1][wofs] = a0; *(short8*)&As[p^1][wofs + 8] = a1;
      *(short8*)&Bs[p^1][wofs] = b0; *(short8*)&Bs[p^1][wofs + 8] = b1;
    }
    __syncthreads();
    p ^= 1;
  }
  const int rbase = bm*128 + wr*64, cbase = bn*128 + wc*64;
  #pragma unroll
  for (int i = 0; i < 4; i++) {
    #pragma unroll
    for (int j = 0; j < 4; j++) {
      int col = cbase + j*16 + r16;
      #pragma unroll
      for (int e = 0; e < 4; e++) {
        int row = rbase + i*16 + kb*4 + e;
        if (row < NROWS) {
          float v = acc[i][j][e];
          if (col < ZLD) {
            zxO[(size_t)row*ZLD + col] = f2bf(v);
          } else if (col < DIP) {
            int hh = col - ZLD;
            float d = v + dtbias[hh];
            d = (d > 20.f) ? d : log1pf(expf(d));
            dtO[(size_t)row*NH + hh] = d;
          }
        }
      }
    }
  }
}

// ---- GEMM1: x += rmsnorm-scaled gated zx @ Wo ; rs from ssq; BK=32 dbuf ----
__global__ __launch_bounds__(256)
void gemm_out(const u16* __restrict__ A, const float* __restrict__ ssq,
              const float* __restrict__ gw, const u16* __restrict__ BT,
              float* __restrict__ X)
{
  __shared__ __align__(16) u16 As[2][128*40];
  __shared__ __align__(16) u16 Bs[2][128*40];
  __shared__ float gwl[DI];
  const int t = threadIdx.x;
  const int nid = xcd_swz(blockIdx.y*6 + blockIdx.x, 6*131);
  const int bm = nid / 6, bn = nid % 6;
  const int lane = t & 63, wave = t >> 6;
  const int wr = wave >> 1, wc = wave & 1;
  const int r16 = lane & 15, kb = lane >> 4;

  for (int i = t; i < DI; i += 256) gwl[i] = gw[i];

  const int m = t >> 1, half = t & 1;
  const int grow = bm*128 + m;
  const bool valid = grow < NROWS;
  const float rs = valid ? rsqrtf(ssq[grow] * (1.f/1536.f) + EPSF) : 0.f;
  const u16* gA = A + (size_t)(valid ? grow : 0)*ZLD + half*16;
  const u16* gB = BT + (size_t)(bn*128 + m)*DI + half*16;
  const int wofs = m*40 + half*16;

  short8 ra0 = {}, ra1 = {}, b0, b1;
  b0 = LD8(gB); b1 = LD8(gB + 8);
  if (valid) { ra0 = LD8(gA); ra1 = LD8(gA + 8); }
  __syncthreads();
  {
    const int c0 = half*16;
    short8 ta0, ta1;
    #pragma unroll
    for (int j = 0; j < 8; j++) ta0[j] = (short)f2bf(bf2f((u16)ra0[j]) * rs * gwl[c0 + j]);
    #pragma unroll
    for (int j = 0; j < 8; j++) ta1[j] = (short)f2bf(bf2f((u16)ra1[j]) * rs * gwl[c0 + 8 + j]);
    *(short8*)&As[0][wofs] = ta0; *(short8*)&As[0][wofs + 8] = ta1;
    *(short8*)&Bs[0][wofs] = b0;  *(short8*)&Bs[0][wofs + 8] = b1;
  }
  __syncthreads();

  f32x4 acc[4][4] = {};
  int p = 0;
  for (int kt = 0; kt < DI; kt += 32) {
    const bool more = (kt + 32 < DI);
    if (more) {
      b0 = LD8(gB + kt + 32); b1 = LD8(gB + kt + 40);
      if (valid) { ra0 = LD8(gA + kt + 32); ra1 = LD8(gA + kt + 40); }
    }
    bf16x8 af[4], bfr[4];
    #pragma unroll
    for (int i = 0; i < 4; i++) af[i]  = *(const bf16x8*)&As[p][(wr*64 + i*16 + r16)*40 + kb*8];
    #pragma unroll
    for (int i = 0; i < 4; i++) bfr[i] = *(const bf16x8*)&Bs[p][(wc*64 + i*16 + r16)*40 + kb*8];
    #pragma unroll
    for (int i = 0; i < 4; i++)
      #pragma unroll
      for (int j = 0; j < 4; j++)
        acc[i][j] = __builtin_amdgcn_mfma_f32_16x16x32_bf16(af[i], bfr[j], acc[i][j], 0, 0, 0);
    if (more) {
      const int c0 = kt + 32 + half*16;
      short8 ta0, ta1;
      #pragma unroll
      for (int j = 0; j < 8; j++) ta0[j] = (short)f2bf(bf2f((u16)ra0[j]) * rs * gwl[c0 + j]);
      #pragma unroll
      for (int j = 0; j < 8; j++) ta1[j] = (short)f2bf(bf2f((u16)ra1[j]) * rs * gwl[c0 + 8 + j]);
      *(short8*)&As[p^1][wofs] = ta0; *(short8*)&As[p^1][wofs + 8] = ta1;
      *(short8*)&Bs[p^1][wofs] = b0;  *(short8*)&Bs[p^1][wofs + 8] = b1;
    }
    __syncthreads();
    p ^= 1;
  }
  const int rbase = bm*128 + wr*64, cbase = bn*128 + wc*64;
  #pragma unroll
  for (int i = 0; i < 4; i++) {
    #pragma unroll
    for (int j = 0; j < 4; j++) {
      int col = cbase + j*16 + r16;
      #pragma unroll
      for (int e = 0; e < 4; e++) {
        int row = rbase + i*16 + kb*4 + e;
        if (row < NROWS) X[(size_t)row*DM + col] += acc[i][j][e];
      }
    }
  }
}

// ======================= chunked SSD =======================

// ---- dtcs: per (b,c,h) prefix sums & weights ----
__global__ __launch_bounds__(128)
void dtcs_kernel(const float* __restrict__ dt, const float* __restrict__ alog,
                 float* __restrict__ csb, float* __restrict__ dtvb,
                 float* __restrict__ wjsb, float* __restrict__ dtot)
{
  const int id = blockIdx.x;
  const int h = id % NH; const int c = (id / NH) % NCH; const int b = id / (NH*NCH);
  const int t = threadIdx.x;
  const int base = c*CHK;
  int rows = LTOT - base; if (rows > CHK) rows = CHK;
  __shared__ float cs[128];
  float dv = 0.f;
  if (t < rows) dv = dt[(size_t)(b*LTOT + base + t)*NH + h];
  const float aexp = __expf(alog[h]);
  cs[t] = -dv * aexp;
  __syncthreads();
  for (int off = 1; off < 128; off <<= 1) {
    float add = (t >= off) ? cs[t - off] : 0.f;
    __syncthreads();
    cs[t] += add;
    __syncthreads();
  }
  float csl = cs[127];
  size_t o = (size_t)id*128 + t;
  csb[o] = cs[t];
  dtvb[o] = dv;
  wjsb[o] = __expf(csl - cs[t]) * dv;
  if (t == 0) dtot[id] = __expf(csl);
}

// ---- conv B/C once per (b,chunk); computes Sraw = C @ B^T ; 512 threads ----
__global__ __launch_bounds__(512)
void convBC_kernel(const u16* __restrict__ zx, const float* __restrict__ cw,
                   const float* __restrict__ cb, u16* __restrict__ Ccv,
                   u16* __restrict__ BcvT, u16* __restrict__ Sraw)
{
  const int bc = xcd_swz(blockIdx.x, BATCH*NCH);
  const int b = bc / NCH, c = bc % NCH;
  const int t = threadIdx.x;                 // 0..511
  const int base = c*CHK;
  __shared__ __align__(16) u16 raw[131*RLD + 8];
  __shared__ __align__(16) u16 Bt[128*LDF];
  __shared__ __align__(16) u16 Ct[128*LDF];
  const u16* zb = zx + (size_t)(b*LTOT)*ZLD;

  // stage raw 131 rows x 256 ch (32 short8-segments per row)
  #pragma unroll
  for (int rg = 0; rg < 9; rg++) {
    int idx = rg*512 + t;
    int r = idx >> 5, seg = idx & 31;
    if (r < 131) {
      int g = base - 3 + r;
      short8 v = {};
      if (g >= 0 && g < LTOT) v = LD8(zb + (size_t)g*ZLD + 3072 + seg*8);
      *(short8*)&raw[r*RLD + seg*8] = v;
    }
  }
  __syncthreads();
  // conv: channel (t&255), rows split in two 64-row halves by (t>>8)
  {
    const int cht = t & 255, halfj = t >> 8;
    const int isC = cht >> 7, n = cht & 127;
    const int ch = 1536 + cht;
    float w0 = cw[ch*4+0], w1 = cw[ch*4+1], w2 = cw[ch*4+2], w3 = cw[ch*4+3];
    float bias = cb[ch];
    const int rb = halfj*64;
    float r0 = bf2f(raw[(rb+0)*RLD + cht]);
    float r1 = bf2f(raw[(rb+1)*RLD + cht]);
    float r2 = bf2f(raw[(rb+2)*RLD + cht]);
    u16* dstT = isC ? Ct : Bt;
    #pragma unroll 4
    for (int j = 0; j < 64; j++) {
      float r3 = bf2f(raw[(rb + j + 3)*RLD + cht]);
      float o = bias + w0*r0 + w1*r1 + w2*r2 + w3*r3;
      dstT[(rb + j)*LDF + n] = f2bf(siluf(o));
      r0 = r1; r1 = r2; r2 = r3;
    }
  }
  __syncthreads();
  // write Ccv [l][n] (128 rows x 16 segs)
  #pragma unroll
  for (int rg = 0; rg < 4; rg++) {
    int idx = rg*512 + t;
    int r = idx >> 4, seg = idx & 15;
    int g = base + r;
    if (g < LTOT)
      *(short8*)(Ccv + (size_t)(b*LTOT + g)*128 + seg*8) = *(const short8*)&Ct[r*LDF + seg*8];
  }
  // write BcvT [n][j] (128 n x 16 segs)
  u16* bT = BcvT + (size_t)bc*16384;
  #pragma unroll
  for (int rg = 0; rg < 4; rg++) {
    int idx = rg*512 + t;
    int n = idx >> 4, js = (idx & 15)*8;
    short8 v;
    #pragma unroll
    for (int k = 0; k < 8; k++) v[k] = (short)Bt[(js + k)*LDF + n];
    *(short8*)(bT + n*128 + js) = v;
  }
  // Sraw[i][j] = sum_n Ct[i][n]*Bt[j][n] ; 8 waves, 16 rows each
  {
    const int lane = t & 63, wave = t >> 6;
    const int r16 = lane & 15, kb = lane >> 4;
    f32x4 acc[8] = {};
    #pragma unroll
    for (int kt = 0; kt < 4; kt++) {
      bf16x8 af = *(const bf16x8*)&Ct[(wave*16 + r16)*LDF + kt*32 + kb*8];
      #pragma unroll
      for (int nj = 0; nj < 8; nj++) {
        bf16x8 bfr = *(const bf16x8*)&Bt[(nj*16 + r16)*LDF + kt*32 + kb*8];
        acc[nj] = __builtin_amdgcn_mfma_f32_16x16x32_bf16(af, bfr, acc[nj], 0, 0, 0);
      }
    }
    u16* sdst = Sraw + (size_t)bc*16384;
    #pragma unroll
    for (int nj = 0; nj < 8; nj++)
      #pragma unroll
      for (int e = 0; e < 4; e++) {
        int i = wave*16 + kb*4 + e;
        int j = nj*16 + r16;
        sdst[i*128 + j] = f2bf(acc[nj][e]);
      }
  }
}

// ---- K1: per-chunk state ----
__global__ __launch_bounds__(256)
void chunk_state_kernel(const u16* __restrict__ zx, const float* __restrict__ wjsb,
                        const float* __restrict__ cw, const float* __restrict__ cb,
                        const u16* __restrict__ BcvT, u16* __restrict__ cstat)
{
  const int id = xcd_swz(blockIdx.x, NBLK);
  const int h = id % NH; const int c = (id / NH) % NCH; const int b = id / (NH*NCH);
  const int t = threadIdx.x;
  const int base = c*CHK;

  __shared__ __align__(16) u16 Bbuf[128*LDF];
  __shared__ __align__(16) u16 xbuf[131*XLD + 8];
  __shared__ float wjs[128];

  const u16* zb = zx + (size_t)(b*LTOT)*ZLD;
  if (t < 128) wjs[t] = wjsb[(size_t)id*128 + t];
  {
    const u16* bT = BcvT + (size_t)(b*NCH + c)*16384;
    #pragma unroll
    for (int rg = 0; rg < 8; rg++) {
      int idx = rg*256 + t;
      int n = idx >> 4, js = (idx & 15)*8;
      *(short8*)&Bbuf[n*LDF + js] = LD8(bT + n*128 + js);
    }
  }
  #pragma unroll
  for (int rg = 0; rg < 5; rg++) {
    int r = rg*32 + (t >> 3);
    int seg = t & 7;
    if (r < 131) {
      int g = base - 3 + r;
      short8 v = {};
      if (g >= 0 && g < LTOT) v = LD8(zb + (size_t)g*ZLD + 1536 + h*HD + seg*8);
      *(short8*)&xbuf[r*XLD + seg*8] = v;
    }
  }
  __syncthreads();

  const int p_ = t & 63, jq = t >> 6;
  u32 pkx[16];
  {
    const int ch = h*HD + p_;
    float w0 = cw[ch*4+0], w1 = cw[ch*4+1], w2 = cw[ch*4+2], w3 = cw[ch*4+3];
    float bias = cb[ch];
    const int rb = jq*32;
    float r0 = bf2f(xbuf[(rb+0)*XLD + p_]);
    float r1 = bf2f(xbuf[(rb+1)*XLD + p_]);
    float r2 = bf2f(xbuf[(rb+2)*XLD + p_]);
    #pragma unroll
    for (int k2 = 0; k2 < 16; k2++) {
      float r3 = bf2f(xbuf[(rb + 2*k2 + 3)*XLD + p_]);
      float o0 = bias + w0*r0 + w1*r1 + w2*r2 + w3*r3;
      float r4 = bf2f(xbuf[(rb + 2*k2 + 4)*XLD + p_]);
      float o1 = bias + w0*r1 + w1*r2 + w2*r3 + w3*r4;
      float s0 = siluf(o0) * wjs[rb + 2*k2];
      float s1 = siluf(o1) * wjs[rb + 2*k2 + 1];
      pkx[k2] = (u32)f2bf(s0) | ((u32)f2bf(s1) << 16);
      r0 = r2; r1 = r3; r2 = r4;
    }
  }
  __syncthreads();
  #pragma unroll
  for (int q = 0; q < 4; q++) {
    u32x4 v; v[0] = pkx[q*4]; v[1] = pkx[q*4+1]; v[2] = pkx[q*4+2]; v[3] = pkx[q*4+3];
    *(u32x4*)&xbuf[p_*LDF + jq*32 + q*8] = v;
  }
  __syncthreads();

  const int lane = t & 63, wave = t >> 6;
  const int r16 = lane & 15, kb = lane >> 4;
  const int n0 = wave*32;
  f32x4 acc[4][2] = {};
  #pragma unroll
  for (int kt = 0; kt < 4; kt++) {
    bf16x8 af[4], bfr[2];
    #pragma unroll
    for (int m = 0; m < 4; m++) af[m] = *(const bf16x8*)&xbuf[(m*16 + r16)*LDF + kt*32 + kb*8];
    #pragma unroll
    for (int nn = 0; nn < 2; nn++) bfr[nn] = *(const bf16x8*)&Bbuf[(n0 + nn*16 + r16)*LDF + kt*32 + kb*8];
    #pragma unroll
    for (int m = 0; m < 4; m++)
      #pragma unroll
      for (int nn = 0; nn < 2; nn++)
        acc[m][nn] = __builtin_amdgcn_mfma_f32_16x16x32_bf16(af[m], bfr[nn], acc[m][nn], 0, 0, 0);
  }
  u16* dst = cstat + (size_t)id*64*128;
  #pragma unroll
  for (int m = 0; m < 4; m++)
    #pragma unroll
    for (int nn = 0; nn < 2; nn++)
      #pragma unroll
      for (int e = 0; e < 4; e++) {
        int p = m*16 + kb*4 + e;
        int n = n0 + nn*16 + r16;
        dst[p*128 + n] = f2bf(acc[m][nn][e]);
      }
}

// ---- K2: inter-chunk scan; 4 blocks per (b,h), each owns 2048 elems ----
__global__ __launch_bounds__(256)
void state_scan_kernel(u16* __restrict__ cstat, const float* __restrict__ dtot)
{
  const int blk = blockIdx.x;
  const int b = blk / (NH*4);
  const int rest = blk % (NH*4);
  const int h = rest >> 2, sec = rest & 3;
  const int t = threadIdx.x;
  const int eofs = sec*2048 + t*8;           // element offset within 8192-slab
  float run[8];
  #pragma unroll
  for (int k = 0; k < 8; k++) run[k] = 0.f;
  size_t id0 = (size_t)(b*NCH)*NH + h;
  short8 cur = LD8(cstat + id0*8192 + eofs);
  float d = dtot[id0];
  for (int c = 0; c < NCH; ++c) {
    size_t id = (size_t)(b*NCH + c)*NH + h;
    u16* slab = cstat + id*8192 + eofs;
    short8 nxt = {}; float nd = 0.f;
    if (c + 1 < NCH) {
      nxt = LD8(slab + (size_t)NH*8192);
      nd = dtot[id + NH];
    }
    short8 out;
    #pragma unroll
    for (int k = 0; k < 8; k++) {
      float csv = bf2f((u16)cur[k]);
      out[k] = (short)f2bf(run[k]);
      run[k] = run[k]*d + csv;
    }
    *(short8*)slab = out;
    cur = nxt;
    d = nd;
  }
}

// ---- K3: per-chunk output; masked staging of precomputed Sraw; fused ssq ----
__global__ __launch_bounds__(512, 4)
void chunk_output_kernel(u16* __restrict__ zx, const float* __restrict__ csb,
                         const float* __restrict__ dtvb, const float* __restrict__ cw,
                         const float* __restrict__ cb, const float* __restrict__ Dvec,
                         const u16* __restrict__ Sraw, const u16* __restrict__ Ccv,
                         const u16* __restrict__ cstat, float* __restrict__ ssq)
{
  const int id = xcd_swz(blockIdx.x, NBLK);
  const int h = id % NH; const int c = (id / NH) % NCH; const int b = id / (NH*NCH);
  const int t = threadIdx.x;
  const int base = c*CHK;
  int rows = LTOT - base; if (rows > CHK) rows = CHK;

  __shared__ __align__(16) u16 Bc[128*LDF];
  __shared__ __align__(16) u16 stT[64*LDF];
  __shared__ __align__(16) u16 xbuf[131*XLD + 8];
  __shared__ float dtv[128];
  __shared__ float cs[128];

  const u16* zb = zx + (size_t)(b*LTOT)*ZLD;
  const size_t crow0 = (size_t)(b*LTOT)*128;
  if (t < 128) {
    cs[t]  = csb[(size_t)id*128 + t];
    dtv[t] = dtvb[(size_t)id*128 + t];
  }
  {
    const u16* slab = cstat + (size_t)id*8192;
    int p = t >> 3, nb = (t & 7)*16;
    *(short8*)&stT[p*LDF + nb]     = LD8(slab + p*128 + nb);
    *(short8*)&stT[p*LDF + nb + 8] = LD8(slab + p*128 + nb + 8);
  }
  #pragma unroll
  for (int rg = 0; rg < 3; rg++) {
    int r = rg*64 + (t >> 3);
    int seg = t & 7;
    if (r < 131) {
      int g = base - 3 + r;
      short8 v = {};
      if (g >= 0 && g < LTOT) v = LD8(zb + (size_t)g*ZLD + 1536 + h*HD + seg*8);
      *(short8*)&xbuf[r*XLD + seg*8] = v;
    }
  }
  __syncthreads();

  const int p_ = t & 63, jq = t >> 6;
  u32 pkx[8];
  {
    const int ch = h*HD + p_;
    float w0 = cw[ch*4+0], w1 = cw[ch*4+1], w2 = cw[ch*4+2], w3 = cw[ch*4+3];
    float bias = cb[ch];
    const int rb = jq*16;
    float r0 = bf2f(xbuf[(rb+0)*XLD + p_]);
    float r1 = bf2f(xbuf[(rb+1)*XLD + p_]);
    float r2 = bf2f(xbuf[(rb+2)*XLD + p_]);
    #pragma unroll
    for (int k2 = 0; k2 < 8; k2++) {
      float r3 = bf2f(xbuf[(rb + 2*k2 + 3)*XLD + p_]);
      float o0 = bias + w0*r0 + w1*r1 + w2*r2 + w3*r3;
      float r4 = bf2f(xbuf[(rb + 2*k2 + 4)*XLD + p_]);
      float o1 = bias + w0*r1 + w1*r2 + w2*r3 + w3*r4;
      int j0 = rb + 2*k2;
      u32 lo = (j0     < rows) ? (u32)f2bf(siluf(o0)) : 0u;
      u32 hi = (j0 + 1 < rows) ? (u32)f2bf(siluf(o1)) : 0u;
      pkx[k2] = lo | (hi << 16);
      r0 = r2; r1 = r3; r2 = r4;
    }
  }
  {
    const u16* sS = Sraw + (size_t)(b*NCH + c)*16384;
    #pragma unroll
    for (int q = 0; q < 4; q++) {
      int idx = q*512 + t;
      int i = idx >> 4, seg = (idx & 15)*8;
      short8 s = LD8(sS + i*128 + seg);
      float csi = cs[i];
      short8 o;
      #pragma unroll
      for (int k = 0; k < 8; k++) {
        int j = seg + k;
        float f = 0.f;
        if (j <= i && i < rows) f = __expf(csi - cs[j]) * dtv[j];
        o[k] = (short)f2bf(bf2f((u16)s[k]) * f);
      }
      *(short8*)&Bc[i*LDF + seg] = o;
    }
  }
  __syncthreads();
  {
    u32x4 v0; v0[0] = pkx[0]; v0[1] = pkx[1]; v0[2] = pkx[2]; v0[3] = pkx[3];
    u32x4 v1; v1[0] = pkx[4]; v1[1] = pkx[5]; v1[2] = pkx[6]; v1[3] = pkx[7];
    *(u32x4*)&xbuf[p_*LDF + jq*16]     = v0;
    *(u32x4*)&xbuf[p_*LDF + jq*16 + 8] = v1;
  }
  __syncthreads();

  const int lane = t & 63, wave = t >> 6;
  const int r16 = lane & 15, kb = lane >> 4;

  {
    const int iq = wave;
    bf16x8 cF[4];
    {
      int i = iq*16 + r16;
      int g = base + i; if (g >= LTOT) g = base;
      #pragma unroll
      for (int kt = 0; kt < 4; kt++)
        cF[kt] = *(const bf16x8*)(Ccv + crow0 + (size_t)g*128 + kt*32 + kb*8);
    }
    f32x4 accY[4] = {};
    #pragma unroll
    for (int kt = 0; kt < 4; kt++) {
      bf16x8 af = *(const bf16x8*)&Bc[(iq*16 + r16)*LDF + kt*32 + kb*8];
      #pragma unroll
      for (int n = 0; n < 4; n++) {
        bf16x8 bfr = *(const bf16x8*)&xbuf[(n*16 + r16)*LDF + kt*32 + kb*8];
        accY[n] = __builtin_amdgcn_mfma_f32_16x16x32_bf16(af, bfr, accY[n], 0, 0, 0);
      }
    }
    f32x4 accS[4] = {};
    #pragma unroll
    for (int kt = 0; kt < 4; kt++) {
      #pragma unroll
      for (int n = 0; n < 4; n++) {
        bf16x8 bfr = *(const bf16x8*)&stT[(n*16 + r16)*LDF + kt*32 + kb*8];
        accS[n] = __builtin_amdgcn_mfma_f32_16x16x32_bf16(cF[kt], bfr, accS[n], 0, 0, 0);
      }
    }
    const float dcoef = Dvec[h];
    #pragma unroll
    for (int e = 0; e < 4; e++) {
      int i = iq*16 + kb*4 + e;
      if (i < rows) {
        float sc = __expf(cs[i]);
        size_t orow = (size_t)(b*LTOT + base + i)*ZLD + h*HD;
        float g2 = 0.f;
        #pragma unroll
        for (int n = 0; n < 4; n++) {
          int p = n*16 + r16;
          float xv = bf2f(xbuf[p*LDF + i]);
          float yv = accY[n][e] + sc*accS[n][e] + dcoef*xv;
          float gv = yv * siluf(bf2f(zx[orow + p]));
          zx[orow + p] = f2bf(gv);
          g2 += gv*gv;
        }
        g2 += __shfl_xor(g2, 1);
        g2 += __shfl_xor(g2, 2);
        g2 += __shfl_xor(g2, 4);
        g2 += __shfl_xor(g2, 8);
        if (r16 == 0) atomicAdd(&ssq[b*LTOT + base + i], g2);
      }
    }
  }
}

// ---- head ----
__global__ __launch_bounds__(256)
void head_kernel(const float* __restrict__ x, const float* __restrict__ tw,
                 const float* __restrict__ tb, const float* __restrict__ im64,
                 float* __restrict__ out, float* __restrict__ partial)
{
  int bj = blockIdx.x;
  int b = bj >> 12, j = bj & 4095;
  int row = b*LTOT + 65 + j;
  const float* xr = x + (size_t)row*DM;
  int t = threadIdx.x;
  float p0 = 0, p1 = 0, p2 = 0;
  for (int k = t; k < 768; k += 256) {
    float xv = xr[k];
    p0 += xv*tw[k*3 + 0]; p1 += xv*tw[k*3 + 1]; p2 += xv*tw[k*3 + 2];
  }
  __shared__ float sh[4];
  p0 = blockSum256(p0, sh);
  p1 = blockSum256(p1, sh);
  p2 = blockSum256(p2, sh);
  if (t == 0) {
    float y0 = p0 + tb[0], y1 = p1 + tb[1], y2 = p2 + tb[2];
    size_t o = (size_t)bj*3;
    out[o] = y0; out[o + 1] = y1; out[o + 2] = y2;
    float d0 = y0 - im64[o], d1 = y1 - im64[o + 1], d2 = y2 - im64[o + 2];
    partial[bj] = d0*d0 + d1*d1 + d2*d2;
  }
}

__global__ __launch_bounds__(256)
void loss_reduce(const float* __restrict__ partial, float* __restrict__ out)
{
  int t = threadIdx.x;
  float s = 0.f;
  for (int i = t; i < BATCH*4096; i += 256) s += partial[i];
  __shared__ float sh[4];
  s = blockSum256(s, sh);
  if (t == 0) out[49152] = s * (1.f/49152.f);
}

// ---- launcher ----
static inline size_t alignup(size_t v){ return (v + 255) & ~(size_t)255; }

extern "C" void kernel_launch(void* const* d_in, const int* in_sizes, int n_in,
                              void* d_out, int out_size, void* d_ws, size_t ws_size,
                              hipStream_t stream)
{
  const float* im8        = (const float*)d_in[0];
  const float* im64       = (const float*)d_in[1];
  const float* from_rgb_w = (const float*)d_in[2];
  const float* from_rgb_b = (const float*)d_in[3];
  const float* to_rgb_w   = (const float*)d_in[4];
  const float* to_rgb_b   = (const float*)d_in[5];
  const float* s0         = (const float*)d_in[6];
  const float* suffix     = (const float*)d_in[7];
  const float* norm0_w    = (const float*)d_in[8];
  const float* norm0_b    = (const float*)d_in[9];
  const float* ln_w       = (const float*)d_in[10];
  const float* ln_b       = (const float*)d_in[11];
  const float* in_proj_w  = (const float*)d_in[12];
  const float* conv_w     = (const float*)d_in[13];
  const float* conv_b     = (const float*)d_in[14];
  const float* dt_bias    = (const float*)d_in[15];
  const float* A_log      = (const float*)d_in[16];
  const float* Dvec       = (const float*)d_in[17];
  const float* gn_w       = (const float*)d_in[18];
  const float* out_proj_w = (const float*)d_in[19];

  char* w = (char*)d_ws;
  size_t off = 0;
  float* x     = (float*)(w + off); off = alignup(off + (size_t)NROWS*DM*4);
  u16*   zx    = (u16*)  (w + off); off = alignup(off + (size_t)NROWS*ZLD*2);
  u16*   scr   = (u16*)  (w + off); off = alignup(off + (size_t)NBLK*64*128*2);
  u16*   Sraw  = (u16*)  (w + off); off = alignup(off + (size_t)BATCH*NCH*16384*2);
  u16*   Ccv   = (u16*)  (w + off); off = alignup(off + (size_t)NROWS*128*2);
  u16*   BcvT  = (u16*)  (w + off); off = alignup(off + (size_t)BATCH*NCH*16384*2);
  float* dt    = (float*)(w + off); off = alignup(off + (size_t)NROWS*NH*4);
  float* csb   = (float*)(w + off); off = alignup(off + (size_t)NBLK*128*4);
  float* dtvb  = (float*)(w + off); off = alignup(off + (size_t)NBLK*128*4);
  float* wjsb  = (float*)(w + off); off = alignup(off + (size_t)NBLK*128*4);
  float* ssq   = (float*)(w + off); off = alignup(off + (size_t)NROWS*4);
  float* dtot  = (float*)(w + off); off = alignup(off + (size_t)NBLK*4);
  float* lpart = (float*)(w + off); off = alignup(off + (size_t)BATCH*4096*4);
  // total ~233.5 MB
  u16* wT    = scr;
  u16* xn    = (u16*)((char*)scr + alignup((size_t)NPAD1*DM*2));
  u16* cstat = scr;

  build_x_kernel<<<NROWS, 256, 0, stream>>>(im8, from_rgb_w, from_rgb_b, s0, suffix,
                                            norm0_w, norm0_b, x);

  for (int i = 0; i < 4; i++) {
    ln_bf16_kernel<<<NROWS, 256, 0, stream>>>(x, ln_w + i*DM, ln_b + i*DM, xn, ssq);
    transp_bf16<<<dim3(NPAD1/32, DM/32), 256, 0, stream>>>(in_proj_w + (size_t)i*DM*DIP, wT, DM, DIP);
    gemm0<<<dim3(27, 131), 256, 0, stream>>>(xn, wT, zx, dt_bias + i*NH, dt);
    dtcs_kernel<<<NBLK, 128, 0, stream>>>(dt, A_log + i*NH, csb, dtvb, wjsb, dtot);
    convBC_kernel<<<BATCH*NCH, 512, 0, stream>>>(zx, conv_w + (size_t)i*(DI+2*DS)*4,
        conv_b + i*(DI+2*DS), Ccv, BcvT, Sraw);
    chunk_state_kernel<<<NBLK, 256, 0, stream>>>(zx, wjsb,
        conv_w + (size_t)i*(DI+2*DS)*4, conv_b + i*(DI+2*DS), BcvT, cstat);
    state_scan_kernel<<<BATCH*NH*4, 256, 0, stream>>>(cstat, dtot);
    chunk_output_kernel<<<NBLK, 512, 0, stream>>>(zx, csb, dtvb,
        conv_w + (size_t)i*(DI+2*DS)*4, conv_b + i*(DI+2*DS), Dvec + i*NH, Sraw, Ccv, cstat, ssq);
    transp_bf16<<<dim3(DM/32, DI/32), 256, 0, stream>>>(out_proj_w + (size_t)i*DI*DM, wT, DI, DM);
    gemm_out<<<dim3(6, 131), 256, 0, stream>>>(zx, ssq, gn_w + i*DI, wT, x);
  }

  head_kernel<<<BATCH*4096, 256, 0, stream>>>(x, to_rgb_w, to_rgb_b, im64, (float*)d_out, lpart);
  loss_reduce<<<1, 256, 0, stream>>>(lpart, (float*)d_out);
}

// Round 15
// 1800.760 us; speedup vs baseline: 1.2668x; 1.1029x over previous
//
#include <hip/hip_runtime.h>
#include <hip/hip_bf16.h>
#include <math.h>

// ---- problem constants ----
#define LTOT 4161
#define BATCH 4
#define NROWS (BATCH*LTOT)      // 16644
#define NPAD1 3456
#define DM 768
#define DI 1536
#define DIP 3352
#define ZLD 3328
#define NH 24
#define HD 64
#define DS 128
#define EPSF 1e-5f
#define CHK 128
#define NCH 33
#define NBLK (BATCH*NCH*NH)     // 3168
#define LDF 136
#define XLD 72
#define RLD 264

typedef __attribute__((ext_vector_type(8))) __bf16 bf16x8;
typedef __attribute__((ext_vector_type(4))) float f32x4;
typedef __attribute__((ext_vector_type(8))) short short8;
typedef __attribute__((ext_vector_type(4))) unsigned int u32x4;
typedef unsigned short u16;
typedef unsigned int u32;

static __device__ __forceinline__ u16 f2bf(float f){
  unsigned u = __builtin_bit_cast(unsigned, f);
  u += 0x7FFFu + ((u >> 16) & 1u);          // RNE
  return (u16)(u >> 16);
}
static __device__ __forceinline__ float bf2f(u16 v){
  return __builtin_bit_cast(float, ((unsigned)v) << 16);
}
static __device__ __forceinline__ float siluf(float v){ return v / (1.f + __expf(-v)); }

// bijective XCD-chunking remap (m204)
static __device__ __forceinline__ int xcd_swz(int orig, int nwg){
  int xcd = orig & 7;
  int idx = orig >> 3;
  int q = nwg >> 3, r = nwg & 7;
  int base = (xcd < r) ? xcd*(q + 1) : r*(q + 1) + (xcd - r)*q;
  return base + idx;
}

__device__ __forceinline__ float blockSum256(float v, float* sh){
  #pragma unroll
  for (int o = 32; o > 0; o >>= 1) v += __shfl_down(v, o);
  int w = threadIdx.x >> 6;
  if ((threadIdx.x & 63) == 0) sh[w] = v;
  __syncthreads();
  v = sh[0] + sh[1] + sh[2] + sh[3];
  __syncthreads();
  return v;
}

// ---- build x = LN0(concat(s0, h8, zm)) ----
__global__ __launch_bounds__(256)
void build_x_kernel(const float* __restrict__ im8, const float* __restrict__ frw,
                    const float* __restrict__ frb, const float* __restrict__ s0,
                    const float* __restrict__ suffix, const float* __restrict__ w,
                    const float* __restrict__ bb, float* __restrict__ x)
{
  int row = blockIdx.x;
  int b = row / LTOT, l = row % LTOT;
  int t = threadIdx.x;
  __shared__ float sh[4];
  float v[3];
  if (l == 0) {
    #pragma unroll
    for (int i = 0; i < 3; i++) v[i] = s0[t + i*256];
  } else if (l <= 64) {
    int p = l - 1;
    float r0 = im8[(b*64 + p)*3 + 0], r1 = im8[(b*64 + p)*3 + 1], r2 = im8[(b*64 + p)*3 + 2];
    #pragma unroll
    for (int i = 0; i < 3; i++) {
      int d = t + i*256;
      v[i] = r0*frw[d] + r1*frw[768 + d] + r2*frw[1536 + d] + frb[d];
    }
  } else {
    int j = l - 65;
    int p = ((j >> 9) << 3) | ((j & 63) >> 3);
    float r0 = im8[(b*64 + p)*3 + 0], r1 = im8[(b*64 + p)*3 + 1], r2 = im8[(b*64 + p)*3 + 2];
    #pragma unroll
    for (int i = 0; i < 3; i++) {
      int d = t + i*256;
      v[i] = r0*frw[d] + r1*frw[768 + d] + r2*frw[1536 + d] + frb[d] + suffix[(size_t)j*768 + d];
    }
  }
  float s = v[0] + v[1] + v[2];
  s = blockSum256(s, sh);
  float mu = s * (1.f/768.f);
  float q = 0;
  #pragma unroll
  for (int i = 0; i < 3; i++) { float d = v[i] - mu; q += d*d; }
  q = blockSum256(q, sh);
  float rs = rsqrtf(q * (1.f/768.f) + EPSF);
  float* xr = x + (size_t)row*DM;
  #pragma unroll
  for (int i = 0; i < 3; i++) {
    int d = t + i*256;
    xr[d] = (v[i] - mu)*rs*w[d] + bb[d];
  }
}

// ---- per-layer LN -> bf16 ; also zeroes ssq[row] ----
__global__ __launch_bounds__(256)
void ln_bf16_kernel(const float* __restrict__ x, const float* __restrict__ w,
                    const float* __restrict__ bb, u16* __restrict__ out,
                    float* __restrict__ ssq)
{
  int row = blockIdx.x;
  int t = threadIdx.x;
  __shared__ float sh[4];
  const float* xr = x + (size_t)row*DM;
  float v[3];
  #pragma unroll
  for (int i = 0; i < 3; i++) v[i] = xr[t + i*256];
  if (t == 0) ssq[row] = 0.f;
  float s = v[0] + v[1] + v[2];
  s = blockSum256(s, sh);
  float mu = s * (1.f/768.f);
  float q = 0;
  #pragma unroll
  for (int i = 0; i < 3; i++) { float d = v[i] - mu; q += d*d; }
  q = blockSum256(q, sh);
  float rs = rsqrtf(q * (1.f/768.f) + EPSF);
  u16* orow = out + (size_t)row*DM;
  #pragma unroll
  for (int i = 0; i < 3; i++) {
    int d = t + i*256;
    orow[d] = f2bf((v[i] - mu)*rs*w[d] + bb[d]);
  }
}

// ---- transpose + f32->bf16 ----
__global__ __launch_bounds__(256)
void transp_bf16(const float* __restrict__ in, u16* __restrict__ out, int K, int N)
{
  __shared__ float tl[32][33];
  int tx = threadIdx.x & 31, ty = threadIdx.x >> 5;
  int n0 = blockIdx.x * 32, k0 = blockIdx.y * 32;
  #pragma unroll
  for (int r = 0; r < 4; r++) {
    int k = k0 + ty + r*8, n = n0 + tx;
    tl[ty + r*8][tx] = (n < N) ? in[(size_t)k*N + n] : 0.f;
  }
  __syncthreads();
  #pragma unroll
  for (int r = 0; r < 4; r++) {
    int n = n0 + ty + r*8, k = k0 + tx;
    out[(size_t)n*K + k] = f2bf(tl[tx][ty + r*8]);
  }
}

#define LD8(p) (*(const short8*)(p))

// ---- GEMM0: zx = xn @ Wi ; BK=32 dbuf; 9-bn supertile swizzle for L2-resident B ----
__global__ __launch_bounds__(256)
void gemm0(const u16* __restrict__ A, const u16* __restrict__ BT,
           u16* __restrict__ zxO, const float* __restrict__ dtbias,
           float* __restrict__ dtO)
{
  __shared__ __align__(16) u16 As[2][128*40];
  __shared__ __align__(16) u16 Bs[2][128*40];
  const int t = threadIdx.x;
  const int nid = xcd_swz(blockIdx.y*27 + blockIdx.x, 27*131);
  const int sc = nid / (131*9);             // supercolumn 0..2
  const int rr = nid % (131*9);
  const int bm = rr / 9, bn = sc*9 + rr % 9;
  const int lane = t & 63, wave = t >> 6;
  const int wr = wave >> 1, wc = wave & 1;
  const int r16 = lane & 15, kb = lane >> 4;

  const int m = t >> 1, half = t & 1;
  const int grow = bm*128 + m;
  const bool valid = grow < NROWS;
  const u16* gA = A + (size_t)(valid ? grow : 0)*DM + half*16;
  const u16* gB = BT + (size_t)(bn*128 + m)*DM + half*16;
  const int wofs = m*40 + half*16;

  short8 a0 = {}, a1 = {}, b0, b1;
  b0 = LD8(gB); b1 = LD8(gB + 8);
  if (valid) { a0 = LD8(gA); a1 = LD8(gA + 8); }
  *(short8*)&As[0][wofs] = a0; *(short8*)&As[0][wofs + 8] = a1;
  *(short8*)&Bs[0][wofs] = b0; *(short8*)&Bs[0][wofs + 8] = b1;
  __syncthreads();

  f32x4 acc[4][4] = {};
  int p = 0;
  for (int kt = 0; kt < DM; kt += 32) {
    const bool more = (kt + 32 < DM);
    if (more) {
      b0 = LD8(gB + kt + 32); b1 = LD8(gB + kt + 40);
      if (valid) { a0 = LD8(gA + kt + 32); a1 = LD8(gA + kt + 40); }
    }
    bf16x8 af[4], bfr[4];
    #pragma unroll
    for (int i = 0; i < 4; i++) af[i]  = *(const bf16x8*)&As[p][(wr*64 + i*16 + r16)*40 + kb*8];
    #pragma unroll
    for (int i = 0; i < 4; i++) bfr[i] = *(const bf16x8*)&Bs[p][(wc*64 + i*16 + r16)*40 + kb*8];
    #pragma unroll
    for (int i = 0; i < 4; i++)
      #pragma unroll
      for (int j = 0; j < 4; j++)
        acc[i][j] = __builtin_amdgcn_mfma_f32_16x16x32_bf16(af[i], bfr[j], acc[i][j], 0, 0, 0);
    if (more) {
      *(short8*)&As[p^1][wofs] = a0; *(short8*)&As[p^1][wofs + 8] = a1;
      *(short8*)&Bs[p^1][wofs] = b0; *(short8*)&Bs[p^1][wofs + 8] = b1;
    }
    __syncthreads();
    p ^= 1;
  }
  const int rbase = bm*128 + wr*64, cbase = bn*128 + wc*64;
  #pragma unroll
  for (int i = 0; i < 4; i++) {
    #pragma unroll
    for (int j = 0; j < 4; j++) {
      int col = cbase + j*16 + r16;
      #pragma unroll
      for (int e = 0; e < 4; e++) {
        int row = rbase + i*16 + kb*4 + e;
        if (row < NROWS) {
          float v = acc[i][j][e];
          if (col < ZLD) {
            zxO[(size_t)row*ZLD + col] = f2bf(v);
          } else if (col < DIP) {
            int hh = col - ZLD;
            float d = v + dtbias[hh];
            d = (d > 20.f) ? d : log1pf(expf(d));
            dtO[(size_t)row*NH + hh] = d;
          }
        }
      }
    }
  }
}

// ---- GEMM1: x += rmsnorm-scaled gated zx @ Wo ; rs from ssq; BK=32 dbuf ----
__global__ __launch_bounds__(256)
void gemm_out(const u16* __restrict__ A, const float* __restrict__ ssq,
              const float* __restrict__ gw, const u16* __restrict__ BT,
              float* __restrict__ X)
{
  __shared__ __align__(16) u16 As[2][128*40];
  __shared__ __align__(16) u16 Bs[2][128*40];
  __shared__ float gwl[DI];
  const int t = threadIdx.x;
  const int nid = xcd_swz(blockIdx.y*6 + blockIdx.x, 6*131);
  const int bm = nid / 6, bn = nid % 6;
  const int lane = t & 63, wave = t >> 6;
  const int wr = wave >> 1, wc = wave & 1;
  const int r16 = lane & 15, kb = lane >> 4;

  for (int i = t; i < DI; i += 256) gwl[i] = gw[i];

  const int m = t >> 1, half = t & 1;
  const int grow = bm*128 + m;
  const bool valid = grow < NROWS;
  const float rs = valid ? rsqrtf(ssq[grow] * (1.f/1536.f) + EPSF) : 0.f;
  const u16* gA = A + (size_t)(valid ? grow : 0)*ZLD + half*16;
  const u16* gB = BT + (size_t)(bn*128 + m)*DI + half*16;
  const int wofs = m*40 + half*16;

  short8 ra0 = {}, ra1 = {}, b0, b1;
  b0 = LD8(gB); b1 = LD8(gB + 8);
  if (valid) { ra0 = LD8(gA); ra1 = LD8(gA + 8); }
  __syncthreads();
  {
    const int c0 = half*16;
    short8 ta0, ta1;
    #pragma unroll
    for (int j = 0; j < 8; j++) ta0[j] = (short)f2bf(bf2f((u16)ra0[j]) * rs * gwl[c0 + j]);
    #pragma unroll
    for (int j = 0; j < 8; j++) ta1[j] = (short)f2bf(bf2f((u16)ra1[j]) * rs * gwl[c0 + 8 + j]);
    *(short8*)&As[0][wofs] = ta0; *(short8*)&As[0][wofs + 8] = ta1;
    *(short8*)&Bs[0][wofs] = b0;  *(short8*)&Bs[0][wofs + 8] = b1;
  }
  __syncthreads();

  f32x4 acc[4][4] = {};
  int p = 0;
  for (int kt = 0; kt < DI; kt += 32) {
    const bool more = (kt + 32 < DI);
    if (more) {
      b0 = LD8(gB + kt + 32); b1 = LD8(gB + kt + 40);
      if (valid) { ra0 = LD8(gA + kt + 32); ra1 = LD8(gA + kt + 40); }
    }
    bf16x8 af[4], bfr[4];
    #pragma unroll
    for (int i = 0; i < 4; i++) af[i]  = *(const bf16x8*)&As[p][(wr*64 + i*16 + r16)*40 + kb*8];
    #pragma unroll
    for (int i = 0; i < 4; i++) bfr[i] = *(const bf16x8*)&Bs[p][(wc*64 + i*16 + r16)*40 + kb*8];
    #pragma unroll
    for (int i = 0; i < 4; i++)
      #pragma unroll
      for (int j = 0; j < 4; j++)
        acc[i][j] = __builtin_amdgcn_mfma_f32_16x16x32_bf16(af[i], bfr[j], acc[i][j], 0, 0, 0);
    if (more) {
      const int c0 = kt + 32 + half*16;
      short8 ta0, ta1;
      #pragma unroll
      for (int j = 0; j < 8; j++) ta0[j] = (short)f2bf(bf2f((u16)ra0[j]) * rs * gwl[c0 + j]);
      #pragma unroll
      for (int j = 0; j < 8; j++) ta1[j] = (short)f2bf(bf2f((u16)ra1[j]) * rs * gwl[c0 + 8 + j]);
      *(short8*)&As[p^1][wofs] = ta0; *(short8*)&As[p^1][wofs + 8] = ta1;
      *(short8*)&Bs[p^1][wofs] = b0;  *(short8*)&Bs[p^1][wofs + 8] = b1;
    }
    __syncthreads();
    p ^= 1;
  }
  const int rbase = bm*128 + wr*64, cbase = bn*128 + wc*64;
  #pragma unroll
  for (int i = 0; i < 4; i++) {
    #pragma unroll
    for (int j = 0; j < 4; j++) {
      int col = cbase + j*16 + r16;
      #pragma unroll
      for (int e = 0; e < 4; e++) {
        int row = rbase + i*16 + kb*4 + e;
        if (row < NROWS) X[(size_t)row*DM + col] += acc[i][j][e];
      }
    }
  }
}

// ======================= chunked SSD =======================

// ---- dtcs: per (b,c,h) prefix sums & weights ----
__global__ __launch_bounds__(128)
void dtcs_kernel(const float* __restrict__ dt, const float* __restrict__ alog,
                 float* __restrict__ csb, float* __restrict__ dtvb,
                 float* __restrict__ wjsb, float* __restrict__ dtot)
{
  const int id = blockIdx.x;
  const int h = id % NH; const int c = (id / NH) % NCH; const int b = id / (NH*NCH);
  const int t = threadIdx.x;
  const int base = c*CHK;
  int rows = LTOT - base; if (rows > CHK) rows = CHK;
  __shared__ float cs[128];
  float dv = 0.f;
  if (t < rows) dv = dt[(size_t)(b*LTOT + base + t)*NH + h];
  const float aexp = __expf(alog[h]);
  cs[t] = -dv * aexp;
  __syncthreads();
  for (int off = 1; off < 128; off <<= 1) {
    float add = (t >= off) ? cs[t - off] : 0.f;
    __syncthreads();
    cs[t] += add;
    __syncthreads();
  }
  float csl = cs[127];
  size_t o = (size_t)id*128 + t;
  csb[o] = cs[t];
  dtvb[o] = dv;
  wjsb[o] = __expf(csl - cs[t]) * dv;
  if (t == 0) dtot[id] = __expf(csl);
}

// ---- conv B/C once per (b,chunk); computes Sraw = C @ B^T ; 512 threads ----
__global__ __launch_bounds__(512)
void convBC_kernel(const u16* __restrict__ zx, const float* __restrict__ cw,
                   const float* __restrict__ cb, u16* __restrict__ Ccv,
                   u16* __restrict__ BcvT, u16* __restrict__ Sraw)
{
  const int bc = xcd_swz(blockIdx.x, BATCH*NCH);
  const int b = bc / NCH, c = bc % NCH;
  const int t = threadIdx.x;
  const int base = c*CHK;
  __shared__ __align__(16) u16 raw[131*RLD + 8];
  __shared__ __align__(16) u16 Bt[128*LDF];
  __shared__ __align__(16) u16 Ct[128*LDF];
  const u16* zb = zx + (size_t)(b*LTOT)*ZLD;

  #pragma unroll
  for (int rg = 0; rg < 9; rg++) {
    int idx = rg*512 + t;
    int r = idx >> 5, seg = idx & 31;
    if (r < 131) {
      int g = base - 3 + r;
      short8 v = {};
      if (g >= 0 && g < LTOT) v = LD8(zb + (size_t)g*ZLD + 3072 + seg*8);
      *(short8*)&raw[r*RLD + seg*8] = v;
    }
  }
  __syncthreads();
  {
    const int cht = t & 255, halfj = t >> 8;
    const int isC = cht >> 7, n = cht & 127;
    const int ch = 1536 + cht;
    float w0 = cw[ch*4+0], w1 = cw[ch*4+1], w2 = cw[ch*4+2], w3 = cw[ch*4+3];
    float bias = cb[ch];
    const int rb = halfj*64;
    float r0 = bf2f(raw[(rb+0)*RLD + cht]);
    float r1 = bf2f(raw[(rb+1)*RLD + cht]);
    float r2 = bf2f(raw[(rb+2)*RLD + cht]);
    u16* dstT = isC ? Ct : Bt;
    #pragma unroll 4
    for (int j = 0; j < 64; j++) {
      float r3 = bf2f(raw[(rb + j + 3)*RLD + cht]);
      float o = bias + w0*r0 + w1*r1 + w2*r2 + w3*r3;
      dstT[(rb + j)*LDF + n] = f2bf(siluf(o));
      r0 = r1; r1 = r2; r2 = r3;
    }
  }
  __syncthreads();
  #pragma unroll
  for (int rg = 0; rg < 4; rg++) {
    int idx = rg*512 + t;
    int r = idx >> 4, seg = idx & 15;
    int g = base + r;
    if (g < LTOT)
      *(short8*)(Ccv + (size_t)(b*LTOT + g)*128 + seg*8) = *(const short8*)&Ct[r*LDF + seg*8];
  }
  u16* bT = BcvT + (size_t)bc*16384;
  #pragma unroll
  for (int rg = 0; rg < 4; rg++) {
    int idx = rg*512 + t;
    int n = idx >> 4, js = (idx & 15)*8;
    short8 v;
    #pragma unroll
    for (int k = 0; k < 8; k++) v[k] = (short)Bt[(js + k)*LDF + n];
    *(short8*)(bT + n*128 + js) = v;
  }
  {
    const int lane = t & 63, wave = t >> 6;
    const int r16 = lane & 15, kb = lane >> 4;
    f32x4 acc[8] = {};
    #pragma unroll
    for (int kt = 0; kt < 4; kt++) {
      bf16x8 af = *(const bf16x8*)&Ct[(wave*16 + r16)*LDF + kt*32 + kb*8];
      #pragma unroll
      for (int nj = 0; nj < 8; nj++) {
        bf16x8 bfr = *(const bf16x8*)&Bt[(nj*16 + r16)*LDF + kt*32 + kb*8];
        acc[nj] = __builtin_amdgcn_mfma_f32_16x16x32_bf16(af, bfr, acc[nj], 0, 0, 0);
      }
    }
    u16* sdst = Sraw + (size_t)bc*16384;
    #pragma unroll
    for (int nj = 0; nj < 8; nj++)
      #pragma unroll
      for (int e = 0; e < 4; e++) {
        int i = wave*16 + kb*4 + e;
        int j = nj*16 + r16;
        sdst[i*128 + j] = f2bf(acc[nj][e]);
      }
  }
}

// ---- K1: per-chunk state; B-operand direct from global BcvT (L2-hot) ----
__global__ __launch_bounds__(256)
void chunk_state_kernel(const u16* __restrict__ zx, const float* __restrict__ wjsb,
                        const float* __restrict__ cw, const float* __restrict__ cb,
                        const u16* __restrict__ BcvT, u16* __restrict__ cstat)
{
  const int id = xcd_swz(blockIdx.x, NBLK);
  const int h = id % NH; const int c = (id / NH) % NCH; const int b = id / (NH*NCH);
  const int t = threadIdx.x;
  const int base = c*CHK;

  __shared__ __align__(16) u16 xbuf[131*XLD + 8];
  __shared__ float wjs[128];

  const u16* zb = zx + (size_t)(b*LTOT)*ZLD;
  if (t < 128) wjs[t] = wjsb[(size_t)id*128 + t];
  #pragma unroll
  for (int rg = 0; rg < 5; rg++) {
    int r = rg*32 + (t >> 3);
    int seg = t & 7;
    if (r < 131) {
      int g = base - 3 + r;
      short8 v = {};
      if (g >= 0 && g < LTOT) v = LD8(zb + (size_t)g*ZLD + 1536 + h*HD + seg*8);
      *(short8*)&xbuf[r*XLD + seg*8] = v;
    }
  }
  __syncthreads();

  const int p_ = t & 63, jq = t >> 6;
  u32 pkx[16];
  {
    const int ch = h*HD + p_;
    float w0 = cw[ch*4+0], w1 = cw[ch*4+1], w2 = cw[ch*4+2], w3 = cw[ch*4+3];
    float bias = cb[ch];
    const int rb = jq*32;
    float r0 = bf2f(xbuf[(rb+0)*XLD + p_]);
    float r1 = bf2f(xbuf[(rb+1)*XLD + p_]);
    float r2 = bf2f(xbuf[(rb+2)*XLD + p_]);
    #pragma unroll
    for (int k2 = 0; k2 < 16; k2++) {
      float r3 = bf2f(xbuf[(rb + 2*k2 + 3)*XLD + p_]);
      float o0 = bias + w0*r0 + w1*r1 + w2*r2 + w3*r3;
      float r4 = bf2f(xbuf[(rb + 2*k2 + 4)*XLD + p_]);
      float o1 = bias + w0*r1 + w1*r2 + w2*r3 + w3*r4;
      float s0 = siluf(o0) * wjs[rb + 2*k2];
      float s1 = siluf(o1) * wjs[rb + 2*k2 + 1];
      pkx[k2] = (u32)f2bf(s0) | ((u32)f2bf(s1) << 16);
      r0 = r2; r1 = r3; r2 = r4;
    }
  }
  __syncthreads();
  #pragma unroll
  for (int q = 0; q < 4; q++) {
    u32x4 v; v[0] = pkx[q*4]; v[1] = pkx[q*4+1]; v[2] = pkx[q*4+2]; v[3] = pkx[q*4+3];
    *(u32x4*)&xbuf[p_*LDF + jq*32 + q*8] = v;
  }
  __syncthreads();

  const int lane = t & 63, wave = t >> 6;
  const int r16 = lane & 15, kb = lane >> 4;
  const int n0 = wave*32;
  const u16* bT = BcvT + (size_t)(b*NCH + c)*16384;
  f32x4 acc[4][2] = {};
  #pragma unroll
  for (int kt = 0; kt < 4; kt++) {
    bf16x8 af[4], bfr[2];
    #pragma unroll
    for (int m = 0; m < 4; m++) af[m] = *(const bf16x8*)&xbuf[(m*16 + r16)*LDF + kt*32 + kb*8];
    #pragma unroll
    for (int nn = 0; nn < 2; nn++)
      bfr[nn] = *(const bf16x8*)(bT + (n0 + nn*16 + r16)*128 + kt*32 + kb*8);
    #pragma unroll
    for (int m = 0; m < 4; m++)
      #pragma unroll
      for (int nn = 0; nn < 2; nn++)
        acc[m][nn] = __builtin_amdgcn_mfma_f32_16x16x32_bf16(af[m], bfr[nn], acc[m][nn], 0, 0, 0);
  }
  u16* dst = cstat + (size_t)id*64*128;
  #pragma unroll
  for (int m = 0; m < 4; m++)
    #pragma unroll
    for (int nn = 0; nn < 2; nn++)
      #pragma unroll
      for (int e = 0; e < 4; e++) {
        int p = m*16 + kb*4 + e;
        int n = n0 + nn*16 + r16;
        dst[p*128 + n] = f2bf(acc[m][nn][e]);
      }
}

// ---- K2: inter-chunk scan; 4 blocks per (b,h) ----
__global__ __launch_bounds__(256)
void state_scan_kernel(u16* __restrict__ cstat, const float* __restrict__ dtot)
{
  const int blk = blockIdx.x;
  const int b = blk / (NH*4);
  const int rest = blk % (NH*4);
  const int h = rest >> 2, sec = rest & 3;
  const int t = threadIdx.x;
  const int eofs = sec*2048 + t*8;
  float run[8];
  #pragma unroll
  for (int k = 0; k < 8; k++) run[k] = 0.f;
  size_t id0 = (size_t)(b*NCH)*NH + h;
  short8 cur = LD8(cstat + id0*8192 + eofs);
  float d = dtot[id0];
  for (int c = 0; c < NCH; ++c) {
    size_t id = (size_t)(b*NCH + c)*NH + h;
    u16* slab = cstat + id*8192 + eofs;
    short8 nxt = {}; float nd = 0.f;
    if (c + 1 < NCH) {
      nxt = LD8(slab + (size_t)NH*8192);
      nd = dtot[id + NH];
    }
    short8 out;
    #pragma unroll
    for (int k = 0; k < 8; k++) {
      float csv = bf2f((u16)cur[k]);
      out[k] = (short)f2bf(run[k]);
      run[k] = run[k]*d + csv;
    }
    *(short8*)slab = out;
    cur = nxt;
    d = nd;
  }
}

// ---- K3: per-chunk output; P and C operands direct from global; fused ssq ----
__global__ __launch_bounds__(512, 4)
void chunk_output_kernel(u16* __restrict__ zx, const float* __restrict__ csb,
                         const float* __restrict__ dtvb, const float* __restrict__ cw,
                         const float* __restrict__ cb, const float* __restrict__ Dvec,
                         const u16* __restrict__ Sraw, const u16* __restrict__ Ccv,
                         const u16* __restrict__ cstat, float* __restrict__ ssq)
{
  const int id = xcd_swz(blockIdx.x, NBLK);
  const int h = id % NH; const int c = (id / NH) % NCH; const int b = id / (NH*NCH);
  const int t = threadIdx.x;
  const int base = c*CHK;
  int rows = LTOT - base; if (rows > CHK) rows = CHK;

  __shared__ __align__(16) u16 stT[64*LDF];       // state_before [p][n]
  __shared__ __align__(16) u16 xbuf[131*XLD + 8]; // raw x -> xc[p][j]
  __shared__ float dtv[128];
  __shared__ float cs[128];

  const u16* zb = zx + (size_t)(b*LTOT)*ZLD;
  const size_t crow0 = (size_t)(b*LTOT)*128;
  if (t < 128) {
    cs[t]  = csb[(size_t)id*128 + t];
    dtv[t] = dtvb[(size_t)id*128 + t];
  }
  {
    const u16* slab = cstat + (size_t)id*8192;
    int p = t >> 3, nb = (t & 7)*16;
    *(short8*)&stT[p*LDF + nb]     = LD8(slab + p*128 + nb);
    *(short8*)&stT[p*LDF + nb + 8] = LD8(slab + p*128 + nb + 8);
  }
  #pragma unroll
  for (int rg = 0; rg < 3; rg++) {
    int r = rg*64 + (t >> 3);
    int seg = t & 7;
    if (r < 131) {
      int g = base - 3 + r;
      short8 v = {};
      if (g >= 0 && g < LTOT) v = LD8(zb + (size_t)g*ZLD + 1536 + h*HD + seg*8);
      *(short8*)&xbuf[r*XLD + seg*8] = v;
    }
  }
  __syncthreads();

  // x conv -> regs
  const int p_ = t & 63, jq = t >> 6;
  u32 pkx[8];
  {
    const int ch = h*HD + p_;
    float w0 = cw[ch*4+0], w1 = cw[ch*4+1], w2 = cw[ch*4+2], w3 = cw[ch*4+3];
    float bias = cb[ch];
    const int rb = jq*16;
    float r0 = bf2f(xbuf[(rb+0)*XLD + p_]);
    float r1 = bf2f(xbuf[(rb+1)*XLD + p_]);
    float r2 = bf2f(xbuf[(rb+2)*XLD + p_]);
    #pragma unroll
    for (int k2 = 0; k2 < 8; k2++) {
      float r3 = bf2f(xbuf[(rb + 2*k2 + 3)*XLD + p_]);
      float o0 = bias + w0*r0 + w1*r1 + w2*r2 + w3*r3;
      float r4 = bf2f(xbuf[(rb + 2*k2 + 4)*XLD + p_]);
      float o1 = bias + w0*r1 + w1*r2 + w2*r3 + w3*r4;
      int j0 = rb + 2*k2;
      u32 lo = (j0     < rows) ? (u32)f2bf(siluf(o0)) : 0u;
      u32 hi = (j0 + 1 < rows) ? (u32)f2bf(siluf(o1)) : 0u;
      pkx[k2] = lo | (hi << 16);
      r0 = r2; r1 = r3; r2 = r4;
    }
  }
  __syncthreads();   // all raw x reads done
  {
    u32x4 v0; v0[0] = pkx[0]; v0[1] = pkx[1]; v0[2] = pkx[2]; v0[3] = pkx[3];
    u32x4 v1; v1[0] = pkx[4]; v1[1] = pkx[5]; v1[2] = pkx[6]; v1[3] = pkx[7];
    *(u32x4*)&xbuf[p_*LDF + jq*16]     = v0;
    *(u32x4*)&xbuf[p_*LDF + jq*16 + 8] = v1;
  }
  __syncthreads();

  const int lane = t & 63, wave = t >> 6;
  const int r16 = lane & 15, kb = lane >> 4;

  // Phase B: Y1 = P @ xc^T with P built in-register from Sraw (masked);
  // Phase C: Y2 = C @ st^T (C direct from global); epilogue with fused ssq
  {
    const int iq = wave;
    const int i_ = iq*16 + r16;
    const float csi = cs[i_];
    const bool irow = (i_ < rows);
    const u16* sSrow = Sraw + (size_t)(b*NCH + c)*16384 + i_*128;
    bf16x8 cF[4];
    {
      int g = base + i_; if (g >= LTOT) g = base;
      #pragma unroll
      for (int kt = 0; kt < 4; kt++)
        cF[kt] = *(const bf16x8*)(Ccv + crow0 + (size_t)g*128 + kt*32 + kb*8);
    }
    f32x4 accY[4] = {};
    #pragma unroll
    for (int kt = 0; kt < 4; kt++) {
      const int cbase0 = kt*32 + kb*8;
      short8 pa = {};
      if (irow && cbase0 <= i_) {
        short8 s = LD8(sSrow + cbase0);
        #pragma unroll
        for (int k = 0; k < 8; k++) {
          int jj = cbase0 + k;
          float f = (jj <= i_) ? __expf(csi - cs[jj]) * dtv[jj] : 0.f;
          pa[k] = (short)f2bf(bf2f((u16)s[k]) * f);
        }
      }
      bf16x8 af = __builtin_bit_cast(bf16x8, pa);
      #pragma unroll
      for (int n = 0; n < 4; n++) {
        bf16x8 bfr = *(const bf16x8*)&xbuf[(n*16 + r16)*LDF + kt*32 + kb*8];
        accY[n] = __builtin_amdgcn_mfma_f32_16x16x32_bf16(af, bfr, accY[n], 0, 0, 0);
      }
    }
    f32x4 accS[4] = {};
    #pragma unroll
    for (int kt = 0; kt < 4; kt++) {
      #pragma unroll
      for (int n = 0; n < 4; n++) {
        bf16x8 bfr = *(const bf16x8*)&stT[(n*16 + r16)*LDF + kt*32 + kb*8];
        accS[n] = __builtin_amdgcn_mfma_f32_16x16x32_bf16(cF[kt], bfr, accS[n], 0, 0, 0);
      }
    }
    const float dcoef = Dvec[h];
    #pragma unroll
    for (int e = 0; e < 4; e++) {
      int i = iq*16 + kb*4 + e;
      if (i < rows) {
        float sc = __expf(cs[i]);
        size_t orow = (size_t)(b*LTOT + base + i)*ZLD + h*HD;
        float g2 = 0.f;
        #pragma unroll
        for (int n = 0; n < 4; n++) {
          int p = n*16 + r16;
          float xv = bf2f(xbuf[p*LDF + i]);
          float yv = accY[n][e] + sc*accS[n][e] + dcoef*xv;
          float gv = yv * siluf(bf2f(zx[orow + p]));
          zx[orow + p] = f2bf(gv);
          g2 += gv*gv;
        }
        g2 += __shfl_xor(g2, 1);
        g2 += __shfl_xor(g2, 2);
        g2 += __shfl_xor(g2, 4);
        g2 += __shfl_xor(g2, 8);
        if (r16 == 0) atomicAdd(&ssq[b*LTOT + base + i], g2);
      }
    }
  }
}

// ---- head ----
__global__ __launch_bounds__(256)
void head_kernel(const float* __restrict__ x, const float* __restrict__ tw,
                 const float* __restrict__ tb, const float* __restrict__ im64,
                 float* __restrict__ out, float* __restrict__ partial)
{
  int bj = blockIdx.x;
  int b = bj >> 12, j = bj & 4095;
  int row = b*LTOT + 65 + j;
  const float* xr = x + (size_t)row*DM;
  int t = threadIdx.x;
  float p0 = 0, p1 = 0, p2 = 0;
  for (int k = t; k < 768; k += 256) {
    float xv = xr[k];
    p0 += xv*tw[k*3 + 0]; p1 += xv*tw[k*3 + 1]; p2 += xv*tw[k*3 + 2];
  }
  __shared__ float sh[4];
  p0 = blockSum256(p0, sh);
  p1 = blockSum256(p1, sh);
  p2 = blockSum256(p2, sh);
  if (t == 0) {
    float y0 = p0 + tb[0], y1 = p1 + tb[1], y2 = p2 + tb[2];
    size_t o = (size_t)bj*3;
    out[o] = y0; out[o + 1] = y1; out[o + 2] = y2;
    float d0 = y0 - im64[o], d1 = y1 - im64[o + 1], d2 = y2 - im64[o + 2];
    partial[bj] = d0*d0 + d1*d1 + d2*d2;
  }
}

__global__ __launch_bounds__(256)
void loss_reduce(const float* __restrict__ partial, float* __restrict__ out)
{
  int t = threadIdx.x;
  float s = 0.f;
  for (int i = t; i < BATCH*4096; i += 256) s += partial[i];
  __shared__ float sh[4];
  s = blockSum256(s, sh);
  if (t == 0) out[49152] = s * (1.f/49152.f);
}

// ---- launcher ----
static inline size_t alignup(size_t v){ return (v + 255) & ~(size_t)255; }

extern "C" void kernel_launch(void* const* d_in, const int* in_sizes, int n_in,
                              void* d_out, int out_size, void* d_ws, size_t ws_size,
                              hipStream_t stream)
{
  const float* im8        = (const float*)d_in[0];
  const float* im64       = (const float*)d_in[1];
  const float* from_rgb_w = (const float*)d_in[2];
  const float* from_rgb_b = (const float*)d_in[3];
  const float* to_rgb_w   = (const float*)d_in[4];
  const float* to_rgb_b   = (const float*)d_in[5];
  const float* s0         = (const float*)d_in[6];
  const float* suffix     = (const float*)d_in[7];
  const float* norm0_w    = (const float*)d_in[8];
  const float* norm0_b    = (const float*)d_in[9];
  const float* ln_w       = (const float*)d_in[10];
  const float* ln_b       = (const float*)d_in[11];
  const float* in_proj_w  = (const float*)d_in[12];
  const float* conv_w     = (const float*)d_in[13];
  const float* conv_b     = (const float*)d_in[14];
  const float* dt_bias    = (const float*)d_in[15];
  const float* A_log      = (const float*)d_in[16];
  const float* Dvec       = (const float*)d_in[17];
  const float* gn_w       = (const float*)d_in[18];
  const float* out_proj_w = (const float*)d_in[19];

  char* w = (char*)d_ws;
  size_t off = 0;
  float* x     = (float*)(w + off); off = alignup(off + (size_t)NROWS*DM*4);
  u16*   zx    = (u16*)  (w + off); off = alignup(off + (size_t)NROWS*ZLD*2);
  u16*   scr   = (u16*)  (w + off); off = alignup(off + (size_t)NBLK*64*128*2);
  u16*   Sraw  = (u16*)  (w + off); off = alignup(off + (size_t)BATCH*NCH*16384*2);
  u16*   Ccv   = (u16*)  (w + off); off = alignup(off + (size_t)NROWS*128*2);
  u16*   BcvT  = (u16*)  (w + off); off = alignup(off + (size_t)BATCH*NCH*16384*2);
  float* dt    = (float*)(w + off); off = alignup(off + (size_t)NROWS*NH*4);
  float* csb   = (float*)(w + off); off = alignup(off + (size_t)NBLK*128*4);
  float* dtvb  = (float*)(w + off); off = alignup(off + (size_t)NBLK*128*4);
  float* wjsb  = (float*)(w + off); off = alignup(off + (size_t)NBLK*128*4);
  float* ssq   = (float*)(w + off); off = alignup(off + (size_t)NROWS*4);
  float* dtot  = (float*)(w + off); off = alignup(off + (size_t)NBLK*4);
  float* lpart = (float*)(w + off); off = alignup(off + (size_t)BATCH*4096*4);
  // total ~233.5 MB
  u16* wT    = scr;
  u16* xn    = (u16*)((char*)scr + alignup((size_t)NPAD1*DM*2));
  u16* cstat = scr;

  build_x_kernel<<<NROWS, 256, 0, stream>>>(im8, from_rgb_w, from_rgb_b, s0, suffix,
                                            norm0_w, norm0_b, x);

  for (int i = 0; i < 4; i++) {
    ln_bf16_kernel<<<NROWS, 256, 0, stream>>>(x, ln_w + i*DM, ln_b + i*DM, xn, ssq);
    transp_bf16<<<dim3(NPAD1/32, DM/32), 256, 0, stream>>>(in_proj_w + (size_t)i*DM*DIP, wT, DM, DIP);
    gemm0<<<dim3(27, 131), 256, 0, stream>>>(xn, wT, zx, dt_bias + i*NH, dt);
    dtcs_kernel<<<NBLK, 128, 0, stream>>>(dt, A_log + i*NH, csb, dtvb, wjsb, dtot);
    convBC_kernel<<<BATCH*NCH, 512, 0, stream>>>(zx, conv_w + (size_t)i*(DI+2*DS)*4,
        conv_b + i*(DI+2*DS), Ccv, BcvT, Sraw);
    chunk_state_kernel<<<NBLK, 256, 0, stream>>>(zx, wjsb,
        conv_w + (size_t)i*(DI+2*DS)*4, conv_b + i*(DI+2*DS), BcvT, cstat);
    state_scan_kernel<<<BATCH*NH*4, 256, 0, stream>>>(cstat, dtot);
    chunk_output_kernel<<<NBLK, 512, 0, stream>>>(zx, csb, dtvb,
        conv_w + (size_t)i*(DI+2*DS)*4, conv_b + i*(DI+2*DS), Dvec + i*NH, Sraw, Ccv, cstat, ssq);
    transp_bf16<<<dim3(DM/32, DI/32), 256, 0, stream>>>(out_proj_w + (size_t)i*DI*DM, wT, DI, DM);
    gemm_out<<<dim3(6, 131), 256, 0, stream>>>(zx, ssq, gn_w + i*DI, wT, x);
  }

  head_kernel<<<BATCH*4096, 256, 0, stream>>>(x, to_rgb_w, to_rgb_b, im64, (float*)d_out, lpart);
  loss_reduce<<<1, 256, 0, stream>>>(lpart, (float*)d_out);
}